// Round 7
// baseline (413.724 us; speedup 1.0000x reference)
//
#include <hip/hip_runtime.h>
#include <hip/hip_bf16.h>
#include <math.h>

#define NHH 16
#define SS  2048
#define TT  4096            // B*S tokens
#define DQK 192
#define QSCALE 0.07216878364870322f   // 1/sqrt(192)
#define ROPE_C 0.28782313662425574f   // 2*ln(10000)/64

typedef __bf16 bf16x8 __attribute__((ext_vector_type(8)));
typedef float f32x4 __attribute__((ext_vector_type(4)));

#define GLOAD16(gp, lp) __builtin_amdgcn_global_load_lds( \
    (const __attribute__((address_space(1))) void*)(gp),  \
    (__attribute__((address_space(3))) void*)(lp), 16, 0, 0)

// ---------------------------------------------------------------------------
// Fused fp32 -> bf16 cast of x + all 7 weight tensors.
// ---------------------------------------------------------------------------
#define SEG0 8388608     // x
#define SEG1 11534336    // + wq_down (3145728)
#define SEG2 12582912    // + wkv_down (1048576)
#define SEG3 12713984    // + wk_rope (131072)
#define SEG4 15859712    // + wq_up (3145728)
#define SEG5 17432576    // + wq_rope (1572864)
#define SEG6 19529728    // + wkv_up (2097152)
#define SEG7 23724032    // + wo (4194304)

__global__ __launch_bounds__(256) void cast_all(
        const float* __restrict__ x, const float* __restrict__ wqd,
        const float* __restrict__ wkvd, const float* __restrict__ wkr,
        const float* __restrict__ wqu, const float* __restrict__ wqr,
        const float* __restrict__ wkvu, const float* __restrict__ wo,
        __bf16* __restrict__ xb, __bf16* __restrict__ wqd_b,
        __bf16* __restrict__ wkvd_b, __bf16* __restrict__ wkr_b,
        __bf16* __restrict__ wqu_b, __bf16* __restrict__ wqr_b,
        __bf16* __restrict__ wkvu_b, __bf16* __restrict__ wo_b) {
    const int i = (blockIdx.x * 256 + threadIdx.x) * 8;
    const float* src;
    __bf16* dst;
    int off;
    if (i < SEG0)      { src = x;    dst = xb;     off = i; }
    else if (i < SEG1) { src = wqd;  dst = wqd_b;  off = i - SEG0; }
    else if (i < SEG2) { src = wkvd; dst = wkvd_b; off = i - SEG1; }
    else if (i < SEG3) { src = wkr;  dst = wkr_b;  off = i - SEG2; }
    else if (i < SEG4) { src = wqu;  dst = wqu_b;  off = i - SEG3; }
    else if (i < SEG5) { src = wqr;  dst = wqr_b;  off = i - SEG4; }
    else if (i < SEG6) { src = wkvu; dst = wkvu_b; off = i - SEG5; }
    else               { src = wo;   dst = wo_b;   off = i - SEG6; }
    const float4 a = *(const float4*)(src + off);
    const float4 b = *(const float4*)(src + off + 4);
    __bf16 o[8] = {(__bf16)a.x, (__bf16)a.y, (__bf16)a.z, (__bf16)a.w,
                   (__bf16)b.x, (__bf16)b.y, (__bf16)b.z, (__bf16)b.w};
    *(bf16x8*)(dst + off) = *(const bf16x8*)o;
}

// ---------------------------------------------------------------------------
// RMSNorm: fp32 in -> bf16 out
// ---------------------------------------------------------------------------
__global__ __launch_bounds__(256) void rmsnorm_k(const float* __restrict__ in,
                                                 __bf16* __restrict__ out,
                                                 const float* __restrict__ w, int N) {
    const int row = blockIdx.x;
    const float* xr = in + (size_t)row * N;
    float ss = 0.f;
    for (int i = threadIdx.x; i < N; i += 256) {
        float v = xr[i];
        ss += v * v;
    }
    __shared__ float red[256];
    red[threadIdx.x] = ss;
    __syncthreads();
    for (int s = 128; s > 0; s >>= 1) {
        if (threadIdx.x < s) red[threadIdx.x] += red[threadIdx.x + s];
        __syncthreads();
    }
    const float scale = rsqrtf(red[0] / (float)N + 1e-6f);
    __bf16* orow = out + (size_t)row * N;
    for (int i = threadIdx.x; i < N; i += 256) orow[i] = (__bf16)(xr[i] * scale * w[i]);
}

// ---------------------------------------------------------------------------
// bf16 MFMA NT-GEMM, 4-phase counted-vmcnt schedule (unchanged core from R6).
// MODE 0 uses a 1-D grid of 288: tiles 0..255 = full 128x256 tiles over
// N=2048; tiles 256..287 = the 64-wide strip at n0=2048 (cheap: only 3
// staged chunks, only wn==0 waves compute) so stragglers are short.
// ---------------------------------------------------------------------------
template<int MODE>
__global__ __launch_bounds__(512, 1) void gemm8(
        const __bf16* __restrict__ A,
        const __bf16* __restrict__ W0, const __bf16* __restrict__ W1,
        const __bf16* __restrict__ W2,
        float* __restrict__ F0, float* __restrict__ F1,
        __bf16* __restrict__ B0, __bf16* __restrict__ B1,
        int M, int N, int K) {
    __shared__ __bf16 lds[3 * 24576];
    const int tid = threadIdx.x;
    const int w = tid >> 6, l = tid & 63;
    const int lr = l & 15, lg = l >> 4;
    const int wm = w >> 2, wn = w & 3;

    int m0, n0, nlim;
    if (MODE == 0) {
        const int fb = blockIdx.x;
        if (fb < 256) { m0 = (fb >> 3) * 128; n0 = (fb & 7) * 256; }
        else          { m0 = (fb - 256) * 128; n0 = 2048; }
        nlim = 2112 - n0;
    } else {
        m0 = blockIdx.y * 128; n0 = blockIdx.x * 256; nlim = 256;
    }
    const bool fullB = (nlim >= 256);
    const bool wAct  = (wn * 64 < nlim);

    const int srow = (w << 3) + (l >> 3);       // 0..63 within chunk
    const int scol = (l & 7) << 3;
    const int sswz = ((srow >> 1) & 7) << 3;
    const int csw  = scol ^ sswz;

    const __bf16* aptr[2];
#pragma unroll
    for (int a = 0; a < 2; ++a)
        aptr[a] = A + (size_t)(m0 + a * 64 + srow) * K + csw;

    const __bf16* bptr[4];
#pragma unroll
    for (int bb = 0; bb < 4; ++bb) {
        const int n = n0 + bb * 64 + srow;
        const __bf16* wp;
        if (MODE == 0) {
            if (n < 1536)      wp = W0 + (size_t)n * K;
            else if (n < 2048) wp = W1 + (size_t)(n - 1536) * K;
            else if (n < 2112) wp = W2 + (size_t)(n - 2048) * K;
            else               wp = W0;
        } else if (MODE == 1) {
            wp = (n < 2048) ? W0 + (size_t)n * K : W1 + (size_t)(n - 2048) * K;
        } else {
            wp = W0 + (size_t)n * K;
        }
        bptr[bb] = wp + csw;
    }

    auto stA = [&](int t2, int a) {
        GLOAD16(aptr[a] + (size_t)t2 * 64,
                &lds[(t2 % 3) * 24576 + a * 4096 + tid * 8]);
    };
    auto stB = [&](int t2, int b) {
        GLOAD16(bptr[b] + (size_t)t2 * 64,
                &lds[(t2 % 3) * 24576 + 8192 + b * 4096 + tid * 8]);
    };

    const int rswz = ((lr >> 1) & 7) << 3;

    f32x4 acc[4][4];
#pragma unroll
    for (int i = 0; i < 4; ++i)
#pragma unroll
        for (int j = 0; j < 4; ++j) acc[i][j] = (f32x4){0.f, 0.f, 0.f, 0.f};

    const int NT = K >> 6;
#pragma unroll
    for (int t = 0; t < 2; ++t) {
        stA(t, 0); stA(t, 1);
        stB(t, 0);
        if (fullB) { stB(t, 1); stB(t, 2); stB(t, 3); }
    }

    for (int t = 0; t < NT; ++t) {
        if (t + 1 < NT) {
            if (fullB) asm volatile("s_waitcnt vmcnt(6)" ::: "memory");
            else       asm volatile("s_waitcnt vmcnt(3)" ::: "memory");
        } else {
            asm volatile("s_waitcnt vmcnt(0)" ::: "memory");
        }
        __builtin_amdgcn_s_barrier();

        const __bf16* As_ = &lds[(t % 3) * 24576];
        const __bf16* Bs_ = As_ + 8192;
        const bool st = (t + 2 < NT);
        const int t2 = t + 2;

        bf16x8 fa[2][2], fb0[2][2], fb1[2][2];

        // ---- phase 0 ----
        if (wAct) {
#pragma unroll
            for (int i = 0; i < 2; ++i)
#pragma unroll
                for (int kk = 0; kk < 2; ++kk)
                    fa[i][kk] = *(const bf16x8*)&As_[(wm * 64 + i * 16 + lr) * 64 +
                                                     ((kk * 32 + lg * 8) ^ rswz)];
#pragma unroll
            for (int j = 0; j < 2; ++j)
#pragma unroll
                for (int kk = 0; kk < 2; ++kk)
                    fb0[j][kk] = *(const bf16x8*)&Bs_[(wn * 64 + j * 16 + lr) * 64 +
                                                      ((kk * 32 + lg * 8) ^ rswz)];
        }
        if (st) { stA(t2, 0); stA(t2, 1); }
        __builtin_amdgcn_s_barrier();
        if (wAct) {
            __builtin_amdgcn_s_setprio(1);
#pragma unroll
            for (int i = 0; i < 2; ++i)
#pragma unroll
                for (int j = 0; j < 2; ++j)
#pragma unroll
                    for (int kk = 0; kk < 2; ++kk)
                        acc[i][j] = __builtin_amdgcn_mfma_f32_16x16x32_bf16(fa[i][kk], fb0[j][kk], acc[i][j], 0, 0, 0);
            __builtin_amdgcn_s_setprio(0);
        }
        __builtin_amdgcn_s_barrier();

        // ---- phase 1 ----
        if (wAct) {
#pragma unroll
            for (int j = 0; j < 2; ++j)
#pragma unroll
                for (int kk = 0; kk < 2; ++kk)
                    fb1[j][kk] = *(const bf16x8*)&Bs_[(wn * 64 + (j + 2) * 16 + lr) * 64 +
                                                      ((kk * 32 + lg * 8) ^ rswz)];
        }
        if (st) { stB(t2, 0); if (fullB) stB(t2, 1); }
        __builtin_amdgcn_s_barrier();
        if (wAct) {
            __builtin_amdgcn_s_setprio(1);
#pragma unroll
            for (int i = 0; i < 2; ++i)
#pragma unroll
                for (int j = 0; j < 2; ++j)
#pragma unroll
                    for (int kk = 0; kk < 2; ++kk)
                        acc[i][j + 2] = __builtin_amdgcn_mfma_f32_16x16x32_bf16(fa[i][kk], fb1[j][kk], acc[i][j + 2], 0, 0, 0);
            __builtin_amdgcn_s_setprio(0);
        }
        __builtin_amdgcn_s_barrier();

        // ---- phase 2 ----
        if (wAct) {
#pragma unroll
            for (int i = 0; i < 2; ++i)
#pragma unroll
                for (int kk = 0; kk < 2; ++kk)
                    fa[i][kk] = *(const bf16x8*)&As_[(wm * 64 + (i + 2) * 16 + lr) * 64 +
                                                     ((kk * 32 + lg * 8) ^ rswz)];
        }
        if (st && fullB) { stB(t2, 2); stB(t2, 3); }
        __builtin_amdgcn_s_barrier();
        if (wAct) {
            __builtin_amdgcn_s_setprio(1);
#pragma unroll
            for (int i = 0; i < 2; ++i)
#pragma unroll
                for (int j = 0; j < 2; ++j)
#pragma unroll
                    for (int kk = 0; kk < 2; ++kk)
                        acc[i + 2][j + 2] = __builtin_amdgcn_mfma_f32_16x16x32_bf16(fa[i][kk], fb1[j][kk], acc[i + 2][j + 2], 0, 0, 0);
            __builtin_amdgcn_s_setprio(0);
        }
        __builtin_amdgcn_s_barrier();

        // ---- phase 3 (registers only) ----
        if (wAct) {
            __builtin_amdgcn_s_setprio(1);
#pragma unroll
            for (int i = 0; i < 2; ++i)
#pragma unroll
                for (int j = 0; j < 2; ++j)
#pragma unroll
                    for (int kk = 0; kk < 2; ++kk)
                        acc[i + 2][j] = __builtin_amdgcn_mfma_f32_16x16x32_bf16(fa[i][kk], fb0[j][kk], acc[i + 2][j], 0, 0, 0);
            __builtin_amdgcn_s_setprio(0);
        }
    }

    if (!wAct) return;

    // ---- epilogue ----
#pragma unroll
    for (int i = 0; i < 4; ++i) {
#pragma unroll
        for (int j = 0; j < 4; ++j) {
#pragma unroll
            for (int r = 0; r < 4; ++r) {
                const int m = m0 + wm * 64 + i * 16 + lg * 4 + r;
                const int n = n0 + wn * 64 + j * 16 + lr;
                const float v = acc[i][j][r];
                float vp = 0.f;
                if (MODE == 0 || MODE == 1) vp = __shfl_xor(v, 1);
                if (MODE == 0) {
                    if (n < 1536) {
                        F0[(size_t)m * 1536 + n] = v;
                    } else if (n < 2048) {
                        F1[(size_t)m * 512 + (n - 1536)] = v;
                    } else if (n < 2112) {
                        const int jj = n - 2048;
                        const int fi = jj >> 1;
                        const int spos = m & (SS - 1);
                        const float freq = __expf(-ROPE_C * (float)fi);
                        const float ang = (float)spos * freq;
                        const float sn = __sinf(ang), cs = __cosf(ang);
                        const float o = (jj & 1) ? (vp * sn + v * cs) : (v * cs - vp * sn);
                        B0[(size_t)m * 64 + jj] = (__bf16)o;
                    }
                } else if (MODE == 1) {
                    if (n < 2048) {
                        B0[(size_t)m * 3072 + (n >> 7) * 192 + (n & 127)] = (__bf16)(v * QSCALE);
                    } else {
                        const int jj = n - 2048;
                        const int h = jj >> 6, dd = jj & 63;
                        const int fi = dd >> 1;
                        const int spos = m & (SS - 1);
                        const float freq = __expf(-ROPE_C * (float)fi);
                        const float ang = (float)spos * freq;
                        const float sn = __sinf(ang), cs = __cosf(ang);
                        const float o = (dd & 1) ? (vp * sn + v * cs) : (v * cs - vp * sn);
                        B0[(size_t)m * 3072 + h * 192 + 128 + dd] = (__bf16)(o * QSCALE);
                    }
                } else if (MODE == 2) {
                    const int h = n >> 8, off = n & 255;
                    if (off < 128)
                        B0[(size_t)m * 2048 + h * 128 + off] = (__bf16)v;
                    else
                        B1[(((size_t)(m >> 11) * NHH + h) * 128 + (off - 128)) * SS + (m & (SS - 1))] = (__bf16)v;
                } else {
                    F0[(size_t)m * N + n] = v;
                }
            }
        }
    }
}

// ---------------------------------------------------------------------------
// MFMA flash attention v4: 8 waves x 32 q-rows (2 fragment groups sharing
// K/V fragment reads), 256-row q-tile per block, KV tile 64, double-buffered
// LDS, async reg-staging, XCD-aligned mapping, setprio, defer-max.
// Grid 256: flat -> xcd=flat&7, a=flat>>3, t=a&7, g=((a>>3)<<3)|xcd.
// ---------------------------------------------------------------------------
__global__ __launch_bounds__(512, 2) void attn_mfma4(
        const __bf16* __restrict__ q, const __bf16* __restrict__ knope,
        const __bf16* __restrict__ krope, const __bf16* __restrict__ vT,
        __bf16* __restrict__ att) {
    const int flat = blockIdx.x;
    const int xcd = flat & 7;
    const int a0 = flat >> 3;
    const int t = a0 & 7;
    const int g8 = ((a0 >> 3) << 3) | xcd;
    const int h = g8 & 15;
    const int b = g8 >> 4;

    const int tid = threadIdx.x;
    const int w  = tid >> 6;
    const int l  = tid & 63;
    const int lr = l & 15;
    const int lg = l >> 4;

    __shared__ __bf16 Ks[2][64][200];
    __shared__ __bf16 Vs[2][128][72];
    __shared__ __bf16 Ps[8][2][16][72];

    const int rg0 = t * 256 + w * 32;       // wave's rows: rg0..rg0+31
    const int nkt = 4 * t + 4;

    bf16x8 sreg[5];
    auto stage_load = [&](int kv0) {
#pragma unroll
        for (int i = 0; i < 5; ++i) {
            const int gc = tid + 512 * i;
            if (gc < 1536) {
                const int row = gc / 24, cc = gc - row * 24;
                const size_t tt = (size_t)(b * SS + kv0 + row);
                const __bf16* src = (cc < 16)
                    ? knope + tt * 2048 + h * 128 + cc * 8
                    : krope + tt * 64 + (cc - 16) * 8;
                sreg[i] = *(const bf16x8*)src;
            } else {
                const int c = gc - 1536;
                const int row = c >> 3, cc = c & 7;
                sreg[i] = *(const bf16x8*)(vT + (((size_t)b * NHH + h) * 128 + row) * SS
                                              + kv0 + cc * 8);
            }
        }
    };
    auto stage_write = [&](int bi) {
#pragma unroll
        for (int i = 0; i < 5; ++i) {
            const int gc = tid + 512 * i;
            if (gc < 1536) {
                const int row = gc / 24, cc = gc - row * 24;
                *(bf16x8*)&Ks[bi][row][cc * 8] = sreg[i];
            } else {
                const int c = gc - 1536;
                *(bf16x8*)&Vs[bi][c >> 3][(c & 7) * 8] = sreg[i];
            }
        }
    };

    // Q fragments for both groups
    bf16x8 qf[2][6];
#pragma unroll
    for (int grp = 0; grp < 2; ++grp) {
        const __bf16* qb = q + (((size_t)(b * SS + rg0 + grp * 16 + lr)) * NHH + h) * DQK + lg * 8;
#pragma unroll
        for (int c = 0; c < 6; ++c) qf[grp][c] = *(const bf16x8*)(qb + c * 32);
    }

    f32x4 O[2][8];
    float m_r[2][4], l_r[2][4];
#pragma unroll
    for (int grp = 0; grp < 2; ++grp) {
#pragma unroll
        for (int n = 0; n < 8; ++n) O[grp][n] = (f32x4){0.f, 0.f, 0.f, 0.f};
#pragma unroll
        for (int r = 0; r < 4; ++r) { m_r[grp][r] = -INFINITY; l_r[grp][r] = 0.f; }
    }

    stage_load(0);
    stage_write(0);
    __syncthreads();
    int cur = 0;

    for (int kt = 0; kt < nkt; ++kt) {
        const int kv0 = kt * 64;
        const bool hasNext = (kt + 1 < nkt);
        if (hasNext) stage_load(kv0 + 64);

        const bool ga0 = kv0 <= rg0 + 15;
        const bool ga1 = kv0 <= rg0 + 31;
        if (ga1) {
            // ---- QK^T: K-frags read once, used by both groups ----
            f32x4 sc[2][4];
#pragma unroll
            for (int s = 0; s < 4; ++s) {
                const int colb = kv0 + s * 16;
                if (colb <= rg0 + 31) {
                    bf16x8 kf[6];
#pragma unroll
                    for (int c = 0; c < 6; ++c)
                        kf[c] = *(const bf16x8*)&Ks[cur][s * 16 + lr][c * 32 + lg * 8];
                    __builtin_amdgcn_s_setprio(1);
#pragma unroll
                    for (int grp = 0; grp < 2; ++grp) {
                        if (colb <= rg0 + grp * 16 + 15) {
                            f32x4 acc = (f32x4){0.f, 0.f, 0.f, 0.f};
#pragma unroll
                            for (int c = 0; c < 6; ++c)
                                acc = __builtin_amdgcn_mfma_f32_16x16x32_bf16(qf[grp][c], kf[c], acc, 0, 0, 0);
                            sc[grp][s] = acc;
                        } else {
                            sc[grp][s] = (f32x4){-INFINITY, -INFINITY, -INFINITY, -INFINITY};
                        }
                    }
                    __builtin_amdgcn_s_setprio(0);
                } else {
                    sc[0][s] = (f32x4){-INFINITY, -INFINITY, -INFINITY, -INFINITY};
                    sc[1][s] = (f32x4){-INFINITY, -INFINITY, -INFINITY, -INFINITY};
                }
            }

            // ---- softmax per group (defer-max) ----
#pragma unroll
            for (int grp = 0; grp < 2; ++grp) {
                const bool ga = (grp == 0) ? ga0 : ga1;
                if (!ga) continue;
                const int rg = rg0 + grp * 16;
#pragma unroll
                for (int s = 0; s < 4; ++s) {
                    const int col = kv0 + s * 16 + lr;
#pragma unroll
                    for (int r = 0; r < 4; ++r)
                        if (col > rg + lg * 4 + r) sc[grp][s][r] = -INFINITY;
                }
                float mt[4];
#pragma unroll
                for (int r = 0; r < 4; ++r) {
                    float m = fmaxf(fmaxf(sc[grp][0][r], sc[grp][1][r]),
                                    fmaxf(sc[grp][2][r], sc[grp][3][r]));
                    m = fmaxf(m, __shfl_xor(m, 1));
                    m = fmaxf(m, __shfl_xor(m, 2));
                    m = fmaxf(m, __shfl_xor(m, 4));
                    m = fmaxf(m, __shfl_xor(m, 8));
                    mt[r] = m;
                }
                const bool ok = (mt[0] <= m_r[grp][0] + 8.f) && (mt[1] <= m_r[grp][1] + 8.f) &&
                                (mt[2] <= m_r[grp][2] + 8.f) && (mt[3] <= m_r[grp][3] + 8.f);
                if (!__all(ok)) {
#pragma unroll
                    for (int r = 0; r < 4; ++r) {
                        const float mn = fmaxf(m_r[grp][r], mt[r]);
                        const float al = __expf(m_r[grp][r] - mn);
                        m_r[grp][r] = mn;
                        l_r[grp][r] *= al;
#pragma unroll
                        for (int n = 0; n < 8; ++n) O[grp][n][r] *= al;
                    }
                }
#pragma unroll
                for (int s = 0; s < 4; ++s) {
#pragma unroll
                    for (int r = 0; r < 4; ++r) {
                        const float pv = __expf(sc[grp][s][r] - m_r[grp][r]);
                        sc[grp][s][r] = pv;
                        Ps[w][grp][lg * 4 + r][s * 16 + lr] = (__bf16)pv;
                    }
                }
#pragma unroll
                for (int r = 0; r < 4; ++r) {
                    float ls = (sc[grp][0][r] + sc[grp][1][r]) + (sc[grp][2][r] + sc[grp][3][r]);
                    ls += __shfl_xor(ls, 1);
                    ls += __shfl_xor(ls, 2);
                    ls += __shfl_xor(ls, 4);
                    ls += __shfl_xor(ls, 8);
                    l_r[grp][r] += ls;
                }
            }

            // ---- PV: V-frags read once, used by both groups ----
            bf16x8 pf[2][2];
#pragma unroll
            for (int grp = 0; grp < 2; ++grp)
#pragma unroll
                for (int ks = 0; ks < 2; ++ks)
                    pf[grp][ks] = *(const bf16x8*)&Ps[w][grp][lr][ks * 32 + lg * 8];
#pragma unroll
            for (int n = 0; n < 8; ++n) {
                bf16x8 v0 = *(const bf16x8*)&Vs[cur][n * 16 + lr][lg * 8];
                bf16x8 v1 = *(const bf16x8*)&Vs[cur][n * 16 + lr][32 + lg * 8];
                __builtin_amdgcn_s_setprio(1);
                O[0][n] = __builtin_amdgcn_mfma_f32_16x16x32_bf16(pf[0][0], v0, O[0][n], 0, 0, 0);
                O[0][n] = __builtin_amdgcn_mfma_f32_16x16x32_bf16(pf[0][1], v1, O[0][n], 0, 0, 0);
                if (ga1) {
                    O[1][n] = __builtin_amdgcn_mfma_f32_16x16x32_bf16(pf[1][0], v0, O[1][n], 0, 0, 0);
                    O[1][n] = __builtin_amdgcn_mfma_f32_16x16x32_bf16(pf[1][1], v1, O[1][n], 0, 0, 0);
                }
                __builtin_amdgcn_s_setprio(0);
            }
        }

        if (hasNext) stage_write(cur ^ 1);
        __syncthreads();
        cur ^= 1;
    }

    // ---- epilogue ----
#pragma unroll
    for (int grp = 0; grp < 2; ++grp) {
        float inv[4];
#pragma unroll
        for (int r = 0; r < 4; ++r) inv[r] = 1.0f / l_r[grp][r];
#pragma unroll
        for (int n = 0; n < 8; ++n) {
#pragma unroll
            for (int r = 0; r < 4; ++r) {
                const size_t tt = (size_t)(b * SS + rg0 + grp * 16 + lg * 4 + r);
                att[(tt * NHH + h) * 128 + n * 16 + lr] = (__bf16)(O[grp][n][r] * inv[r]);
            }
        }
    }
}

// ---------------------------------------------------------------------------
extern "C" void kernel_launch(void* const* d_in, const int* in_sizes, int n_in,
                              void* d_out, int out_size, void* d_ws, size_t ws_size,
                              hipStream_t stream) {
    (void)in_sizes; (void)n_in; (void)out_size; (void)ws_size;
    const float* x        = (const float*)d_in[0];
    const float* wq_down  = (const float*)d_in[1];
    const float* wq_up    = (const float*)d_in[2];
    const float* wq_rope  = (const float*)d_in[3];
    const float* q_norm_w = (const float*)d_in[4];
    const float* wkv_down = (const float*)d_in[5];
    const float* kv_norm_w= (const float*)d_in[6];
    const float* wkv_up   = (const float*)d_in[7];
    const float* wk_rope  = (const float*)d_in[8];
    const float* wo       = (const float*)d_in[9];
    float* out = (float*)d_out;

    char* ws = (char*)d_ws;
    float*  q_c   = (float*)(ws + 0);            // 24MB fp32 [4096][1536]
    __bf16* att   = (__bf16*)(ws + 0);           // 16MB bf16, aliases dead q_c
    float*  kv_c  = (float*)(ws + 25165824);     // 8MB fp32 [4096][512]
    __bf16* xb    = (__bf16*)(ws + 33554432);    // 16MB bf16 [4096][2048]
    __bf16* vT    = (__bf16*)(ws + 33554432);    // 16MB bf16, aliases dead xb
    __bf16* qc_b  = (__bf16*)(ws + 50331648);    // 12MB bf16 [4096][1536]
    __bf16* kvc_b = (__bf16*)(ws + 62914560);    // 4MB bf16 [4096][512]
    __bf16* krope = (__bf16*)(ws + 67108864);    // 0.5MB bf16 [4096][64]
    __bf16* qbuf  = (__bf16*)(ws + 67633152);    // 24MB bf16 [4096][3072]
    __bf16* wqd_b = (__bf16*)(ws + 92798976);    // 6MB
    __bf16* wqu_b = (__bf16*)(ws + 99090432);    // 6MB
    __bf16* wqr_b = (__bf16*)(ws + 105381888);   // 3MB
    __bf16* wkvd_b= (__bf16*)(ws + 108527616);   // 2MB
    __bf16* wkvu_b= (__bf16*)(ws + 110624768);   // 4MB
    __bf16* wkr_b = (__bf16*)(ws + 114819072);   // 0.25MB
    __bf16* wo_b  = (__bf16*)(ws + 115081216);   // 8MB (end 123469824)
    __bf16* knope = (__bf16*)d_out;              // 16MB bf16 in d_out (dead until final GEMM)

    const dim3 blk(256);

    cast_all<<<dim3(SEG7 / 2048), blk, 0, stream>>>(
        x, wq_down, wkv_down, wk_rope, wq_up, wq_rope, wkv_up, wo,
        xb, wqd_b, wkvd_b, wkr_b, wqu_b, wqr_b, wkvu_b, wo_b);

    // X-GEMM: 1-D grid, 256 full tiles + 32 cheap strip tiles last
    gemm8<0><<<dim3(288), dim3(512), 0, stream>>>(xb, wqd_b, wkvd_b, wkr_b,
                                                  q_c, kv_c, krope, nullptr, TT, 2112, 2048);

    rmsnorm_k<<<dim3(TT), blk, 0, stream>>>(q_c, qc_b, q_norm_w, 1536);
    rmsnorm_k<<<dim3(TT), blk, 0, stream>>>(kv_c, kvc_b, kv_norm_w, 512);

    gemm8<1><<<dim3(12, 32), dim3(512), 0, stream>>>(qc_b, wqu_b, wqr_b, nullptr,
                                                     nullptr, nullptr, qbuf, nullptr, TT, 3072, 1536);

    gemm8<2><<<dim3(16, 32), dim3(512), 0, stream>>>(kvc_b, wkvu_b, nullptr, nullptr,
                                                     nullptr, nullptr, knope, vT, TT, 4096, 512);

    attn_mfma4<<<dim3(256), dim3(512), 0, stream>>>(qbuf, knope, krope, vT, att);

    gemm8<3><<<dim3(8, 32), dim3(512), 0, stream>>>(att, wo_b, nullptr, nullptr,
                                                    out, nullptr, nullptr, nullptr, TT, 2048, 2048);
}

// Round 8
// 382.818 us; speedup vs baseline: 1.0807x; 1.0807x over previous
//
#include <hip/hip_runtime.h>
#include <hip/hip_bf16.h>
#include <math.h>

#define NHH 16
#define SS  2048
#define TT  4096            // B*S tokens
#define DQK 192
#define QSCALE 0.07216878364870322f   // 1/sqrt(192)
#define ROPE_C 0.28782313662425574f   // 2*ln(10000)/64

typedef __bf16 bf16x8 __attribute__((ext_vector_type(8)));
typedef float f32x4 __attribute__((ext_vector_type(4)));

#define GLOAD16(gp, lp) __builtin_amdgcn_global_load_lds( \
    (const __attribute__((address_space(1))) void*)(gp),  \
    (__attribute__((address_space(3))) void*)(lp), 16, 0, 0)

// ---------------------------------------------------------------------------
// Fused fp32 -> bf16 cast of x + all 7 weight tensors.
// ---------------------------------------------------------------------------
#define SEG0 8388608     // x
#define SEG1 11534336    // + wq_down (3145728)
#define SEG2 12582912    // + wkv_down (1048576)
#define SEG3 12713984    // + wk_rope (131072)
#define SEG4 15859712    // + wq_up (3145728)
#define SEG5 17432576    // + wq_rope (1572864)
#define SEG6 19529728    // + wkv_up (2097152)
#define SEG7 23724032    // + wo (4194304)

__global__ __launch_bounds__(256) void cast_all(
        const float* __restrict__ x, const float* __restrict__ wqd,
        const float* __restrict__ wkvd, const float* __restrict__ wkr,
        const float* __restrict__ wqu, const float* __restrict__ wqr,
        const float* __restrict__ wkvu, const float* __restrict__ wo,
        __bf16* __restrict__ xb, __bf16* __restrict__ wqd_b,
        __bf16* __restrict__ wkvd_b, __bf16* __restrict__ wkr_b,
        __bf16* __restrict__ wqu_b, __bf16* __restrict__ wqr_b,
        __bf16* __restrict__ wkvu_b, __bf16* __restrict__ wo_b) {
    const int i = (blockIdx.x * 256 + threadIdx.x) * 8;
    const float* src;
    __bf16* dst;
    int off;
    if (i < SEG0)      { src = x;    dst = xb;     off = i; }
    else if (i < SEG1) { src = wqd;  dst = wqd_b;  off = i - SEG0; }
    else if (i < SEG2) { src = wkvd; dst = wkvd_b; off = i - SEG1; }
    else if (i < SEG3) { src = wkr;  dst = wkr_b;  off = i - SEG2; }
    else if (i < SEG4) { src = wqu;  dst = wqu_b;  off = i - SEG3; }
    else if (i < SEG5) { src = wqr;  dst = wqr_b;  off = i - SEG4; }
    else if (i < SEG6) { src = wkvu; dst = wkvu_b; off = i - SEG5; }
    else               { src = wo;   dst = wo_b;   off = i - SEG6; }
    const float4 a = *(const float4*)(src + off);
    const float4 b = *(const float4*)(src + off + 4);
    __bf16 o[8] = {(__bf16)a.x, (__bf16)a.y, (__bf16)a.z, (__bf16)a.w,
                   (__bf16)b.x, (__bf16)b.y, (__bf16)b.z, (__bf16)b.w};
    *(bf16x8*)(dst + off) = *(const bf16x8*)o;
}

// ---------------------------------------------------------------------------
// RMSNorm: fp32 in -> bf16 out
// ---------------------------------------------------------------------------
__global__ __launch_bounds__(256) void rmsnorm_k(const float* __restrict__ in,
                                                 __bf16* __restrict__ out,
                                                 const float* __restrict__ w, int N) {
    const int row = blockIdx.x;
    const float* xr = in + (size_t)row * N;
    float ss = 0.f;
    for (int i = threadIdx.x; i < N; i += 256) {
        float v = xr[i];
        ss += v * v;
    }
    __shared__ float red[256];
    red[threadIdx.x] = ss;
    __syncthreads();
    for (int s = 128; s > 0; s >>= 1) {
        if (threadIdx.x < s) red[threadIdx.x] += red[threadIdx.x + s];
        __syncthreads();
    }
    const float scale = rsqrtf(red[0] / (float)N + 1e-6f);
    __bf16* orow = out + (size_t)row * N;
    for (int i = threadIdx.x; i < N; i += 256) orow[i] = (__bf16)(xr[i] * scale * w[i]);
}

// ---------------------------------------------------------------------------
// bf16 MFMA NT-GEMM, 4-phase counted-vmcnt schedule (unchanged from R7).
// ---------------------------------------------------------------------------
template<int MODE>
__global__ __launch_bounds__(512, 1) void gemm8(
        const __bf16* __restrict__ A,
        const __bf16* __restrict__ W0, const __bf16* __restrict__ W1,
        const __bf16* __restrict__ W2,
        float* __restrict__ F0, float* __restrict__ F1,
        __bf16* __restrict__ B0, __bf16* __restrict__ B1,
        int M, int N, int K) {
    __shared__ __bf16 lds[3 * 24576];
    const int tid = threadIdx.x;
    const int w = tid >> 6, l = tid & 63;
    const int lr = l & 15, lg = l >> 4;
    const int wm = w >> 2, wn = w & 3;

    int m0, n0, nlim;
    if (MODE == 0) {
        const int fb = blockIdx.x;
        if (fb < 256) { m0 = (fb >> 3) * 128; n0 = (fb & 7) * 256; }
        else          { m0 = (fb - 256) * 128; n0 = 2048; }
        nlim = 2112 - n0;
    } else {
        m0 = blockIdx.y * 128; n0 = blockIdx.x * 256; nlim = 256;
    }
    const bool fullB = (nlim >= 256);
    const bool wAct  = (wn * 64 < nlim);

    const int srow = (w << 3) + (l >> 3);
    const int scol = (l & 7) << 3;
    const int sswz = ((srow >> 1) & 7) << 3;
    const int csw  = scol ^ sswz;

    const __bf16* aptr[2];
#pragma unroll
    for (int a = 0; a < 2; ++a)
        aptr[a] = A + (size_t)(m0 + a * 64 + srow) * K + csw;

    const __bf16* bptr[4];
#pragma unroll
    for (int bb = 0; bb < 4; ++bb) {
        const int n = n0 + bb * 64 + srow;
        const __bf16* wp;
        if (MODE == 0) {
            if (n < 1536)      wp = W0 + (size_t)n * K;
            else if (n < 2048) wp = W1 + (size_t)(n - 1536) * K;
            else if (n < 2112) wp = W2 + (size_t)(n - 2048) * K;
            else               wp = W0;
        } else if (MODE == 1) {
            wp = (n < 2048) ? W0 + (size_t)n * K : W1 + (size_t)(n - 2048) * K;
        } else {
            wp = W0 + (size_t)n * K;
        }
        bptr[bb] = wp + csw;
    }

    auto stA = [&](int t2, int a) {
        GLOAD16(aptr[a] + (size_t)t2 * 64,
                &lds[(t2 % 3) * 24576 + a * 4096 + tid * 8]);
    };
    auto stB = [&](int t2, int b) {
        GLOAD16(bptr[b] + (size_t)t2 * 64,
                &lds[(t2 % 3) * 24576 + 8192 + b * 4096 + tid * 8]);
    };

    const int rswz = ((lr >> 1) & 7) << 3;

    f32x4 acc[4][4];
#pragma unroll
    for (int i = 0; i < 4; ++i)
#pragma unroll
        for (int j = 0; j < 4; ++j) acc[i][j] = (f32x4){0.f, 0.f, 0.f, 0.f};

    const int NT = K >> 6;
#pragma unroll
    for (int t = 0; t < 2; ++t) {
        stA(t, 0); stA(t, 1);
        stB(t, 0);
        if (fullB) { stB(t, 1); stB(t, 2); stB(t, 3); }
    }

    for (int t = 0; t < NT; ++t) {
        if (t + 1 < NT) {
            if (fullB) asm volatile("s_waitcnt vmcnt(6)" ::: "memory");
            else       asm volatile("s_waitcnt vmcnt(3)" ::: "memory");
        } else {
            asm volatile("s_waitcnt vmcnt(0)" ::: "memory");
        }
        __builtin_amdgcn_s_barrier();

        const __bf16* As_ = &lds[(t % 3) * 24576];
        const __bf16* Bs_ = As_ + 8192;
        const bool st = (t + 2 < NT);
        const int t2 = t + 2;

        bf16x8 fa[2][2], fb0[2][2], fb1[2][2];

        // ---- phase 0 ----
        if (wAct) {
#pragma unroll
            for (int i = 0; i < 2; ++i)
#pragma unroll
                for (int kk = 0; kk < 2; ++kk)
                    fa[i][kk] = *(const bf16x8*)&As_[(wm * 64 + i * 16 + lr) * 64 +
                                                     ((kk * 32 + lg * 8) ^ rswz)];
#pragma unroll
            for (int j = 0; j < 2; ++j)
#pragma unroll
                for (int kk = 0; kk < 2; ++kk)
                    fb0[j][kk] = *(const bf16x8*)&Bs_[(wn * 64 + j * 16 + lr) * 64 +
                                                      ((kk * 32 + lg * 8) ^ rswz)];
        }
        if (st) { stA(t2, 0); stA(t2, 1); }
        __builtin_amdgcn_s_barrier();
        if (wAct) {
            __builtin_amdgcn_s_setprio(1);
#pragma unroll
            for (int i = 0; i < 2; ++i)
#pragma unroll
                for (int j = 0; j < 2; ++j)
#pragma unroll
                    for (int kk = 0; kk < 2; ++kk)
                        acc[i][j] = __builtin_amdgcn_mfma_f32_16x16x32_bf16(fa[i][kk], fb0[j][kk], acc[i][j], 0, 0, 0);
            __builtin_amdgcn_s_setprio(0);
        }
        __builtin_amdgcn_s_barrier();

        // ---- phase 1 ----
        if (wAct) {
#pragma unroll
            for (int j = 0; j < 2; ++j)
#pragma unroll
                for (int kk = 0; kk < 2; ++kk)
                    fb1[j][kk] = *(const bf16x8*)&Bs_[(wn * 64 + (j + 2) * 16 + lr) * 64 +
                                                      ((kk * 32 + lg * 8) ^ rswz)];
        }
        if (st) { stB(t2, 0); if (fullB) stB(t2, 1); }
        __builtin_amdgcn_s_barrier();
        if (wAct) {
            __builtin_amdgcn_s_setprio(1);
#pragma unroll
            for (int i = 0; i < 2; ++i)
#pragma unroll
                for (int j = 0; j < 2; ++j)
#pragma unroll
                    for (int kk = 0; kk < 2; ++kk)
                        acc[i][j + 2] = __builtin_amdgcn_mfma_f32_16x16x32_bf16(fa[i][kk], fb1[j][kk], acc[i][j + 2], 0, 0, 0);
            __builtin_amdgcn_s_setprio(0);
        }
        __builtin_amdgcn_s_barrier();

        // ---- phase 2 ----
        if (wAct) {
#pragma unroll
            for (int i = 0; i < 2; ++i)
#pragma unroll
                for (int kk = 0; kk < 2; ++kk)
                    fa[i][kk] = *(const bf16x8*)&As_[(wm * 64 + (i + 2) * 16 + lr) * 64 +
                                                     ((kk * 32 + lg * 8) ^ rswz)];
        }
        if (st && fullB) { stB(t2, 2); stB(t2, 3); }
        __builtin_amdgcn_s_barrier();
        if (wAct) {
            __builtin_amdgcn_s_setprio(1);
#pragma unroll
            for (int i = 0; i < 2; ++i)
#pragma unroll
                for (int j = 0; j < 2; ++j)
#pragma unroll
                    for (int kk = 0; kk < 2; ++kk)
                        acc[i + 2][j + 2] = __builtin_amdgcn_mfma_f32_16x16x32_bf16(fa[i][kk], fb1[j][kk], acc[i + 2][j + 2], 0, 0, 0);
            __builtin_amdgcn_s_setprio(0);
        }
        __builtin_amdgcn_s_barrier();

        // ---- phase 3 (registers only) ----
        if (wAct) {
            __builtin_amdgcn_s_setprio(1);
#pragma unroll
            for (int i = 0; i < 2; ++i)
#pragma unroll
                for (int j = 0; j < 2; ++j)
#pragma unroll
                    for (int kk = 0; kk < 2; ++kk)
                        acc[i + 2][j] = __builtin_amdgcn_mfma_f32_16x16x32_bf16(fa[i][kk], fb0[j][kk], acc[i + 2][j], 0, 0, 0);
            __builtin_amdgcn_s_setprio(0);
        }
    }

    if (!wAct) return;

    // ---- epilogue ----
#pragma unroll
    for (int i = 0; i < 4; ++i) {
#pragma unroll
        for (int j = 0; j < 4; ++j) {
#pragma unroll
            for (int r = 0; r < 4; ++r) {
                const int m = m0 + wm * 64 + i * 16 + lg * 4 + r;
                const int n = n0 + wn * 64 + j * 16 + lr;
                const float v = acc[i][j][r];
                float vp = 0.f;
                if (MODE == 0 || MODE == 1) vp = __shfl_xor(v, 1);
                if (MODE == 0) {
                    if (n < 1536) {
                        F0[(size_t)m * 1536 + n] = v;
                    } else if (n < 2048) {
                        F1[(size_t)m * 512 + (n - 1536)] = v;
                    } else if (n < 2112) {
                        const int jj = n - 2048;
                        const int fi = jj >> 1;
                        const int spos = m & (SS - 1);
                        const float freq = __expf(-ROPE_C * (float)fi);
                        const float ang = (float)spos * freq;
                        const float sn = __sinf(ang), cs = __cosf(ang);
                        const float o = (jj & 1) ? (vp * sn + v * cs) : (v * cs - vp * sn);
                        B0[(size_t)m * 64 + jj] = (__bf16)o;
                    }
                } else if (MODE == 1) {
                    if (n < 2048) {
                        B0[(size_t)m * 3072 + (n >> 7) * 192 + (n & 127)] = (__bf16)(v * QSCALE);
                    } else {
                        const int jj = n - 2048;
                        const int h = jj >> 6, dd = jj & 63;
                        const int fi = dd >> 1;
                        const int spos = m & (SS - 1);
                        const float freq = __expf(-ROPE_C * (float)fi);
                        const float ang = (float)spos * freq;
                        const float sn = __sinf(ang), cs = __cosf(ang);
                        const float o = (dd & 1) ? (vp * sn + v * cs) : (v * cs - vp * sn);
                        B0[(size_t)m * 3072 + h * 192 + 128 + dd] = (__bf16)(o * QSCALE);
                    }
                } else if (MODE == 2) {
                    const int h = n >> 8, off = n & 255;
                    if (off < 128)
                        B0[(size_t)m * 2048 + h * 128 + off] = (__bf16)v;
                    else
                        B1[(((size_t)(m >> 11) * NHH + h) * 128 + (off - 128)) * SS + (m & (SS - 1))] = (__bf16)v;
                } else {
                    F0[(size_t)m * N + n] = v;
                }
            }
        }
    }
}

// ---------------------------------------------------------------------------
// MFMA flash attention v5: paired 128-row tiles processed SIMULTANEOUSLY.
// Waves 0-3 own tile A = bx, waves 4-7 own tile B = 15-bx; each wave owns 32
// ADJACENT rows = 2 fragment groups sharing K/V fragment reads. Balanced:
// every block = 34 group-iters. KV tile 64, double-buffered LDS, async
// reg-staging, XCD-aligned mapping, setprio, defer-max.
// ---------------------------------------------------------------------------
__global__ __launch_bounds__(512, 1) void attn_mfma5(
        const __bf16* __restrict__ q, const __bf16* __restrict__ knope,
        const __bf16* __restrict__ krope, const __bf16* __restrict__ vT,
        __bf16* __restrict__ att) {
    const int flat = blockIdx.x;
    const int xcd = flat & 7;
    const int a0 = flat >> 3;
    const int bx = a0 & 7;
    const int g8 = ((a0 >> 3) << 3) | xcd;
    const int h = g8 & 15;
    const int b = g8 >> 4;

    const int tid = threadIdx.x;
    const int w  = tid >> 6;
    const int l  = tid & 63;
    const int lr = l & 15;
    const int lg = l >> 4;

    __shared__ __bf16 Ks[2][64][200];
    __shared__ __bf16 Vs[2][128][72];
    __shared__ __bf16 Ps[8][2][16][72];

    const int tile = (w < 4) ? bx : (15 - bx);
    const int rg0 = tile * 128 + (w & 3) * 32;     // wave rows: rg0..rg0+31
    const int nkt = 2 * (15 - bx) + 2;             // block-wide KV iters
    const int wlim = rg0 + 31;                     // wave causal limit

    bf16x8 sreg[5];
    auto stage_load = [&](int kv0) {
#pragma unroll
        for (int i = 0; i < 5; ++i) {
            const int gc = tid + 512 * i;
            if (gc < 1536) {
                const int row = gc / 24, cc = gc - row * 24;
                const size_t tt = (size_t)(b * SS + kv0 + row);
                const __bf16* src = (cc < 16)
                    ? knope + tt * 2048 + h * 128 + cc * 8
                    : krope + tt * 64 + (cc - 16) * 8;
                sreg[i] = *(const bf16x8*)src;
            } else {
                const int c = gc - 1536;
                const int row = c >> 3, cc = c & 7;
                sreg[i] = *(const bf16x8*)(vT + (((size_t)b * NHH + h) * 128 + row) * SS
                                              + kv0 + cc * 8);
            }
        }
    };
    auto stage_write = [&](int bi) {
#pragma unroll
        for (int i = 0; i < 5; ++i) {
            const int gc = tid + 512 * i;
            if (gc < 1536) {
                const int row = gc / 24, cc = gc - row * 24;
                *(bf16x8*)&Ks[bi][row][cc * 8] = sreg[i];
            } else {
                const int c = gc - 1536;
                *(bf16x8*)&Vs[bi][c >> 3][(c & 7) * 8] = sreg[i];
            }
        }
    };

    // Q fragments for both groups
    bf16x8 qf[2][6];
#pragma unroll
    for (int grp = 0; grp < 2; ++grp) {
        const __bf16* qb = q + (((size_t)(b * SS + rg0 + grp * 16 + lr)) * NHH + h) * DQK + lg * 8;
#pragma unroll
        for (int c = 0; c < 6; ++c) qf[grp][c] = *(const bf16x8*)(qb + c * 32);
    }

    f32x4 O[2][8];
    float m_r[2][4], l_r[2][4];
#pragma unroll
    for (int grp = 0; grp < 2; ++grp) {
#pragma unroll
        for (int n = 0; n < 8; ++n) O[grp][n] = (f32x4){0.f, 0.f, 0.f, 0.f};
#pragma unroll
        for (int r = 0; r < 4; ++r) { m_r[grp][r] = -INFINITY; l_r[grp][r] = 0.f; }
    }

    stage_load(0);
    stage_write(0);
    __syncthreads();
    int cur = 0;

    for (int kt = 0; kt < nkt; ++kt) {
        const int kv0 = kt * 64;
        const bool hasNext = (kt + 1 < nkt);
        if (hasNext) stage_load(kv0 + 64);

        if (kv0 <= wlim) {
            // ---- QK^T: K-frags read once, used by both groups ----
            f32x4 sc[2][4];
#pragma unroll
            for (int s = 0; s < 4; ++s) {
                const int colb = kv0 + s * 16;
                if (colb <= wlim) {
                    bf16x8 kf[6];
#pragma unroll
                    for (int c = 0; c < 6; ++c)
                        kf[c] = *(const bf16x8*)&Ks[cur][s * 16 + lr][c * 32 + lg * 8];
                    __builtin_amdgcn_s_setprio(1);
#pragma unroll
                    for (int grp = 0; grp < 2; ++grp) {
                        if (colb <= rg0 + grp * 16 + 15) {
                            f32x4 acc = (f32x4){0.f, 0.f, 0.f, 0.f};
#pragma unroll
                            for (int c = 0; c < 6; ++c)
                                acc = __builtin_amdgcn_mfma_f32_16x16x32_bf16(qf[grp][c], kf[c], acc, 0, 0, 0);
                            sc[grp][s] = acc;
                        } else {
                            sc[grp][s] = (f32x4){-INFINITY, -INFINITY, -INFINITY, -INFINITY};
                        }
                    }
                    __builtin_amdgcn_s_setprio(0);
                } else {
                    sc[0][s] = (f32x4){-INFINITY, -INFINITY, -INFINITY, -INFINITY};
                    sc[1][s] = (f32x4){-INFINITY, -INFINITY, -INFINITY, -INFINITY};
                }
            }

            // ---- softmax per group (defer-max) ----
#pragma unroll
            for (int grp = 0; grp < 2; ++grp) {
                const int rg = rg0 + grp * 16;
#pragma unroll
                for (int s = 0; s < 4; ++s) {
                    const int col = kv0 + s * 16 + lr;
#pragma unroll
                    for (int r = 0; r < 4; ++r)
                        if (col > rg + lg * 4 + r) sc[grp][s][r] = -INFINITY;
                }
                float mt[4];
#pragma unroll
                for (int r = 0; r < 4; ++r) {
                    float m = fmaxf(fmaxf(sc[grp][0][r], sc[grp][1][r]),
                                    fmaxf(sc[grp][2][r], sc[grp][3][r]));
                    m = fmaxf(m, __shfl_xor(m, 1));
                    m = fmaxf(m, __shfl_xor(m, 2));
                    m = fmaxf(m, __shfl_xor(m, 4));
                    m = fmaxf(m, __shfl_xor(m, 8));
                    mt[r] = m;
                }
                const bool ok = (mt[0] <= m_r[grp][0] + 8.f) && (mt[1] <= m_r[grp][1] + 8.f) &&
                                (mt[2] <= m_r[grp][2] + 8.f) && (mt[3] <= m_r[grp][3] + 8.f);
                if (!__all(ok)) {
#pragma unroll
                    for (int r = 0; r < 4; ++r) {
                        const float mn = fmaxf(m_r[grp][r], mt[r]);
                        const float al = __expf(m_r[grp][r] - mn);
                        m_r[grp][r] = mn;
                        l_r[grp][r] *= al;
#pragma unroll
                        for (int n = 0; n < 8; ++n) O[grp][n][r] *= al;
                    }
                }
#pragma unroll
                for (int s = 0; s < 4; ++s) {
#pragma unroll
                    for (int r = 0; r < 4; ++r) {
                        const float pv = __expf(sc[grp][s][r] - m_r[grp][r]);
                        sc[grp][s][r] = pv;
                        Ps[w][grp][lg * 4 + r][s * 16 + lr] = (__bf16)pv;
                    }
                }
#pragma unroll
                for (int r = 0; r < 4; ++r) {
                    float ls = (sc[grp][0][r] + sc[grp][1][r]) + (sc[grp][2][r] + sc[grp][3][r]);
                    ls += __shfl_xor(ls, 1);
                    ls += __shfl_xor(ls, 2);
                    ls += __shfl_xor(ls, 4);
                    ls += __shfl_xor(ls, 8);
                    l_r[grp][r] += ls;
                }
            }

            // ---- PV: V-frags read once, used by both groups ----
            bf16x8 pf[2][2];
#pragma unroll
            for (int grp = 0; grp < 2; ++grp)
#pragma unroll
                for (int ks = 0; ks < 2; ++ks)
                    pf[grp][ks] = *(const bf16x8*)&Ps[w][grp][lr][ks * 32 + lg * 8];
#pragma unroll
            for (int n = 0; n < 8; ++n) {
                bf16x8 v0 = *(const bf16x8*)&Vs[cur][n * 16 + lr][lg * 8];
                bf16x8 v1 = *(const bf16x8*)&Vs[cur][n * 16 + lr][32 + lg * 8];
                __builtin_amdgcn_s_setprio(1);
                O[0][n] = __builtin_amdgcn_mfma_f32_16x16x32_bf16(pf[0][0], v0, O[0][n], 0, 0, 0);
                O[0][n] = __builtin_amdgcn_mfma_f32_16x16x32_bf16(pf[0][1], v1, O[0][n], 0, 0, 0);
                O[1][n] = __builtin_amdgcn_mfma_f32_16x16x32_bf16(pf[1][0], v0, O[1][n], 0, 0, 0);
                O[1][n] = __builtin_amdgcn_mfma_f32_16x16x32_bf16(pf[1][1], v1, O[1][n], 0, 0, 0);
                __builtin_amdgcn_s_setprio(0);
            }
        }

        if (hasNext) stage_write(cur ^ 1);
        __syncthreads();
        cur ^= 1;
    }

    // ---- epilogue ----
#pragma unroll
    for (int grp = 0; grp < 2; ++grp) {
        float inv[4];
#pragma unroll
        for (int r = 0; r < 4; ++r) inv[r] = 1.0f / l_r[grp][r];
#pragma unroll
        for (int n = 0; n < 8; ++n) {
#pragma unroll
            for (int r = 0; r < 4; ++r) {
                const size_t tt = (size_t)(b * SS + rg0 + grp * 16 + lg * 4 + r);
                att[(tt * NHH + h) * 128 + n * 16 + lr] = (__bf16)(O[grp][n][r] * inv[r]);
            }
        }
    }
}

// ---------------------------------------------------------------------------
extern "C" void kernel_launch(void* const* d_in, const int* in_sizes, int n_in,
                              void* d_out, int out_size, void* d_ws, size_t ws_size,
                              hipStream_t stream) {
    (void)in_sizes; (void)n_in; (void)out_size; (void)ws_size;
    const float* x        = (const float*)d_in[0];
    const float* wq_down  = (const float*)d_in[1];
    const float* wq_up    = (const float*)d_in[2];
    const float* wq_rope  = (const float*)d_in[3];
    const float* q_norm_w = (const float*)d_in[4];
    const float* wkv_down = (const float*)d_in[5];
    const float* kv_norm_w= (const float*)d_in[6];
    const float* wkv_up   = (const float*)d_in[7];
    const float* wk_rope  = (const float*)d_in[8];
    const float* wo       = (const float*)d_in[9];
    float* out = (float*)d_out;

    char* ws = (char*)d_ws;
    float*  q_c   = (float*)(ws + 0);            // 24MB fp32 [4096][1536]
    __bf16* att   = (__bf16*)(ws + 0);           // 16MB bf16, aliases dead q_c
    float*  kv_c  = (float*)(ws + 25165824);     // 8MB fp32 [4096][512]
    __bf16* xb    = (__bf16*)(ws + 33554432);    // 16MB bf16 [4096][2048]
    __bf16* vT    = (__bf16*)(ws + 33554432);    // 16MB bf16, aliases dead xb
    __bf16* qc_b  = (__bf16*)(ws + 50331648);    // 12MB bf16 [4096][1536]
    __bf16* kvc_b = (__bf16*)(ws + 62914560);    // 4MB bf16 [4096][512]
    __bf16* krope = (__bf16*)(ws + 67108864);    // 0.5MB bf16 [4096][64]
    __bf16* qbuf  = (__bf16*)(ws + 67633152);    // 24MB bf16 [4096][3072]
    __bf16* wqd_b = (__bf16*)(ws + 92798976);    // 6MB
    __bf16* wqu_b = (__bf16*)(ws + 99090432);    // 6MB
    __bf16* wqr_b = (__bf16*)(ws + 105381888);   // 3MB
    __bf16* wkvd_b= (__bf16*)(ws + 108527616);   // 2MB
    __bf16* wkvu_b= (__bf16*)(ws + 110624768);   // 4MB
    __bf16* wkr_b = (__bf16*)(ws + 114819072);   // 0.25MB
    __bf16* wo_b  = (__bf16*)(ws + 115081216);   // 8MB (end 123469824)
    __bf16* knope = (__bf16*)d_out;              // 16MB bf16 in d_out (dead until final GEMM)

    const dim3 blk(256);

    cast_all<<<dim3(SEG7 / 2048), blk, 0, stream>>>(
        x, wq_down, wkv_down, wk_rope, wq_up, wq_rope, wkv_up, wo,
        xb, wqd_b, wkvd_b, wkr_b, wqu_b, wqr_b, wkvu_b, wo_b);

    // X-GEMM: 1-D grid, 256 full tiles + 32 cheap strip tiles last
    gemm8<0><<<dim3(288), dim3(512), 0, stream>>>(xb, wqd_b, wkvd_b, wkr_b,
                                                  q_c, kv_c, krope, nullptr, TT, 2112, 2048);

    rmsnorm_k<<<dim3(TT), blk, 0, stream>>>(q_c, qc_b, q_norm_w, 1536);
    rmsnorm_k<<<dim3(TT), blk, 0, stream>>>(kv_c, kvc_b, kv_norm_w, 512);

    gemm8<1><<<dim3(12, 32), dim3(512), 0, stream>>>(qc_b, wqu_b, wqr_b, nullptr,
                                                     nullptr, nullptr, qbuf, nullptr, TT, 3072, 1536);

    gemm8<2><<<dim3(16, 32), dim3(512), 0, stream>>>(kvc_b, wkvu_b, nullptr, nullptr,
                                                     nullptr, nullptr, knope, vT, TT, 4096, 512);

    attn_mfma5<<<dim3(256), dim3(512), 0, stream>>>(qbuf, knope, krope, vT, att);

    gemm8<3><<<dim3(8, 32), dim3(512), 0, stream>>>(att, wo_b, nullptr, nullptr,
                                                    out, nullptr, nullptr, nullptr, TT, 2048, 2048);
}

// Round 9
// 374.812 us; speedup vs baseline: 1.1038x; 1.0214x over previous
//
#include <hip/hip_runtime.h>
#include <hip/hip_bf16.h>
#include <math.h>

#define NHH 16
#define SS  2048
#define TT  4096            // B*S tokens
#define DQK 192
#define QSCALE 0.07216878364870322f   // 1/sqrt(192)
#define ROPE_C 0.28782313662425574f   // 2*ln(10000)/64

typedef __bf16 bf16x8 __attribute__((ext_vector_type(8)));
typedef float f32x4 __attribute__((ext_vector_type(4)));

#define GLOAD16(gp, lp) __builtin_amdgcn_global_load_lds( \
    (const __attribute__((address_space(1))) void*)(gp),  \
    (__attribute__((address_space(3))) void*)(lp), 16, 0, 0)

// ---------------------------------------------------------------------------
// Fused fp32 -> bf16 cast of x + all 7 weight tensors.
// ---------------------------------------------------------------------------
#define SEG0 8388608     // x
#define SEG1 11534336    // + wq_down (3145728)
#define SEG2 12582912    // + wkv_down (1048576)
#define SEG3 12713984    // + wk_rope (131072)
#define SEG4 15859712    // + wq_up (3145728)
#define SEG5 17432576    // + wq_rope (1572864)
#define SEG6 19529728    // + wkv_up (2097152)
#define SEG7 23724032    // + wo (4194304)

__global__ __launch_bounds__(256) void cast_all(
        const float* __restrict__ x, const float* __restrict__ wqd,
        const float* __restrict__ wkvd, const float* __restrict__ wkr,
        const float* __restrict__ wqu, const float* __restrict__ wqr,
        const float* __restrict__ wkvu, const float* __restrict__ wo,
        __bf16* __restrict__ xb, __bf16* __restrict__ wqd_b,
        __bf16* __restrict__ wkvd_b, __bf16* __restrict__ wkr_b,
        __bf16* __restrict__ wqu_b, __bf16* __restrict__ wqr_b,
        __bf16* __restrict__ wkvu_b, __bf16* __restrict__ wo_b) {
    const int i = (blockIdx.x * 256 + threadIdx.x) * 8;
    const float* src;
    __bf16* dst;
    int off;
    if (i < SEG0)      { src = x;    dst = xb;     off = i; }
    else if (i < SEG1) { src = wqd;  dst = wqd_b;  off = i - SEG0; }
    else if (i < SEG2) { src = wkvd; dst = wkvd_b; off = i - SEG1; }
    else if (i < SEG3) { src = wkr;  dst = wkr_b;  off = i - SEG2; }
    else if (i < SEG4) { src = wqu;  dst = wqu_b;  off = i - SEG3; }
    else if (i < SEG5) { src = wqr;  dst = wqr_b;  off = i - SEG4; }
    else if (i < SEG6) { src = wkvu; dst = wkvu_b; off = i - SEG5; }
    else               { src = wo;   dst = wo_b;   off = i - SEG6; }
    const float4 a = *(const float4*)(src + off);
    const float4 b = *(const float4*)(src + off + 4);
    __bf16 o[8] = {(__bf16)a.x, (__bf16)a.y, (__bf16)a.z, (__bf16)a.w,
                   (__bf16)b.x, (__bf16)b.y, (__bf16)b.z, (__bf16)b.w};
    *(bf16x8*)(dst + off) = *(const bf16x8*)o;
}

// ---------------------------------------------------------------------------
// RMSNorm: fp32 in -> bf16 out
// ---------------------------------------------------------------------------
__global__ __launch_bounds__(256) void rmsnorm_k(const float* __restrict__ in,
                                                 __bf16* __restrict__ out,
                                                 const float* __restrict__ w, int N) {
    const int row = blockIdx.x;
    const float* xr = in + (size_t)row * N;
    float ss = 0.f;
    for (int i = threadIdx.x; i < N; i += 256) {
        float v = xr[i];
        ss += v * v;
    }
    __shared__ float red[256];
    red[threadIdx.x] = ss;
    __syncthreads();
    for (int s = 128; s > 0; s >>= 1) {
        if (threadIdx.x < s) red[threadIdx.x] += red[threadIdx.x + s];
        __syncthreads();
    }
    const float scale = rsqrtf(red[0] / (float)N + 1e-6f);
    __bf16* orow = out + (size_t)row * N;
    for (int i = threadIdx.x; i < N; i += 256) orow[i] = (__bf16)(xr[i] * scale * w[i]);
}

// ---------------------------------------------------------------------------
// bf16 MFMA NT-GEMM, 4-phase counted-vmcnt schedule (unchanged from R8).
// ---------------------------------------------------------------------------
template<int MODE>
__global__ __launch_bounds__(512, 1) void gemm8(
        const __bf16* __restrict__ A,
        const __bf16* __restrict__ W0, const __bf16* __restrict__ W1,
        const __bf16* __restrict__ W2,
        float* __restrict__ F0, float* __restrict__ F1,
        __bf16* __restrict__ B0, __bf16* __restrict__ B1,
        int M, int N, int K) {
    __shared__ __bf16 lds[3 * 24576];
    const int tid = threadIdx.x;
    const int w = tid >> 6, l = tid & 63;
    const int lr = l & 15, lg = l >> 4;
    const int wm = w >> 2, wn = w & 3;

    int m0, n0, nlim;
    if (MODE == 0) {
        const int fb = blockIdx.x;
        if (fb < 256) { m0 = (fb >> 3) * 128; n0 = (fb & 7) * 256; }
        else          { m0 = (fb - 256) * 128; n0 = 2048; }
        nlim = 2112 - n0;
    } else {
        m0 = blockIdx.y * 128; n0 = blockIdx.x * 256; nlim = 256;
    }
    const bool fullB = (nlim >= 256);
    const bool wAct  = (wn * 64 < nlim);

    const int srow = (w << 3) + (l >> 3);
    const int scol = (l & 7) << 3;
    const int sswz = ((srow >> 1) & 7) << 3;
    const int csw  = scol ^ sswz;

    const __bf16* aptr[2];
#pragma unroll
    for (int a = 0; a < 2; ++a)
        aptr[a] = A + (size_t)(m0 + a * 64 + srow) * K + csw;

    const __bf16* bptr[4];
#pragma unroll
    for (int bb = 0; bb < 4; ++bb) {
        const int n = n0 + bb * 64 + srow;
        const __bf16* wp;
        if (MODE == 0) {
            if (n < 1536)      wp = W0 + (size_t)n * K;
            else if (n < 2048) wp = W1 + (size_t)(n - 1536) * K;
            else if (n < 2112) wp = W2 + (size_t)(n - 2048) * K;
            else               wp = W0;
        } else if (MODE == 1) {
            wp = (n < 2048) ? W0 + (size_t)n * K : W1 + (size_t)(n - 2048) * K;
        } else {
            wp = W0 + (size_t)n * K;
        }
        bptr[bb] = wp + csw;
    }

    auto stA = [&](int t2, int a) {
        GLOAD16(aptr[a] + (size_t)t2 * 64,
                &lds[(t2 % 3) * 24576 + a * 4096 + tid * 8]);
    };
    auto stB = [&](int t2, int b) {
        GLOAD16(bptr[b] + (size_t)t2 * 64,
                &lds[(t2 % 3) * 24576 + 8192 + b * 4096 + tid * 8]);
    };

    const int rswz = ((lr >> 1) & 7) << 3;

    f32x4 acc[4][4];
#pragma unroll
    for (int i = 0; i < 4; ++i)
#pragma unroll
        for (int j = 0; j < 4; ++j) acc[i][j] = (f32x4){0.f, 0.f, 0.f, 0.f};

    const int NT = K >> 6;
#pragma unroll
    for (int t = 0; t < 2; ++t) {
        stA(t, 0); stA(t, 1);
        stB(t, 0);
        if (fullB) { stB(t, 1); stB(t, 2); stB(t, 3); }
    }

    for (int t = 0; t < NT; ++t) {
        if (t + 1 < NT) {
            if (fullB) asm volatile("s_waitcnt vmcnt(6)" ::: "memory");
            else       asm volatile("s_waitcnt vmcnt(3)" ::: "memory");
        } else {
            asm volatile("s_waitcnt vmcnt(0)" ::: "memory");
        }
        __builtin_amdgcn_s_barrier();

        const __bf16* As_ = &lds[(t % 3) * 24576];
        const __bf16* Bs_ = As_ + 8192;
        const bool st = (t + 2 < NT);
        const int t2 = t + 2;

        bf16x8 fa[2][2], fb0[2][2], fb1[2][2];

        // ---- phase 0 ----
        if (wAct) {
#pragma unroll
            for (int i = 0; i < 2; ++i)
#pragma unroll
                for (int kk = 0; kk < 2; ++kk)
                    fa[i][kk] = *(const bf16x8*)&As_[(wm * 64 + i * 16 + lr) * 64 +
                                                     ((kk * 32 + lg * 8) ^ rswz)];
#pragma unroll
            for (int j = 0; j < 2; ++j)
#pragma unroll
                for (int kk = 0; kk < 2; ++kk)
                    fb0[j][kk] = *(const bf16x8*)&Bs_[(wn * 64 + j * 16 + lr) * 64 +
                                                      ((kk * 32 + lg * 8) ^ rswz)];
        }
        if (st) { stA(t2, 0); stA(t2, 1); }
        __builtin_amdgcn_s_barrier();
        if (wAct) {
            __builtin_amdgcn_s_setprio(1);
#pragma unroll
            for (int i = 0; i < 2; ++i)
#pragma unroll
                for (int j = 0; j < 2; ++j)
#pragma unroll
                    for (int kk = 0; kk < 2; ++kk)
                        acc[i][j] = __builtin_amdgcn_mfma_f32_16x16x32_bf16(fa[i][kk], fb0[j][kk], acc[i][j], 0, 0, 0);
            __builtin_amdgcn_s_setprio(0);
        }
        __builtin_amdgcn_s_barrier();

        // ---- phase 1 ----
        if (wAct) {
#pragma unroll
            for (int j = 0; j < 2; ++j)
#pragma unroll
                for (int kk = 0; kk < 2; ++kk)
                    fb1[j][kk] = *(const bf16x8*)&Bs_[(wn * 64 + (j + 2) * 16 + lr) * 64 +
                                                      ((kk * 32 + lg * 8) ^ rswz)];
        }
        if (st) { stB(t2, 0); if (fullB) stB(t2, 1); }
        __builtin_amdgcn_s_barrier();
        if (wAct) {
            __builtin_amdgcn_s_setprio(1);
#pragma unroll
            for (int i = 0; i < 2; ++i)
#pragma unroll
                for (int j = 0; j < 2; ++j)
#pragma unroll
                    for (int kk = 0; kk < 2; ++kk)
                        acc[i][j + 2] = __builtin_amdgcn_mfma_f32_16x16x32_bf16(fa[i][kk], fb1[j][kk], acc[i][j + 2], 0, 0, 0);
            __builtin_amdgcn_s_setprio(0);
        }
        __builtin_amdgcn_s_barrier();

        // ---- phase 2 ----
        if (wAct) {
#pragma unroll
            for (int i = 0; i < 2; ++i)
#pragma unroll
                for (int kk = 0; kk < 2; ++kk)
                    fa[i][kk] = *(const bf16x8*)&As_[(wm * 64 + (i + 2) * 16 + lr) * 64 +
                                                     ((kk * 32 + lg * 8) ^ rswz)];
        }
        if (st && fullB) { stB(t2, 2); stB(t2, 3); }
        __builtin_amdgcn_s_barrier();
        if (wAct) {
            __builtin_amdgcn_s_setprio(1);
#pragma unroll
            for (int i = 0; i < 2; ++i)
#pragma unroll
                for (int j = 0; j < 2; ++j)
#pragma unroll
                    for (int kk = 0; kk < 2; ++kk)
                        acc[i + 2][j + 2] = __builtin_amdgcn_mfma_f32_16x16x32_bf16(fa[i][kk], fb1[j][kk], acc[i + 2][j + 2], 0, 0, 0);
            __builtin_amdgcn_s_setprio(0);
        }
        __builtin_amdgcn_s_barrier();

        // ---- phase 3 (registers only) ----
        if (wAct) {
            __builtin_amdgcn_s_setprio(1);
#pragma unroll
            for (int i = 0; i < 2; ++i)
#pragma unroll
                for (int j = 0; j < 2; ++j)
#pragma unroll
                    for (int kk = 0; kk < 2; ++kk)
                        acc[i + 2][j] = __builtin_amdgcn_mfma_f32_16x16x32_bf16(fa[i][kk], fb0[j][kk], acc[i + 2][j], 0, 0, 0);
            __builtin_amdgcn_s_setprio(0);
        }
    }

    if (!wAct) return;

    // ---- epilogue ----
#pragma unroll
    for (int i = 0; i < 4; ++i) {
#pragma unroll
        for (int j = 0; j < 4; ++j) {
#pragma unroll
            for (int r = 0; r < 4; ++r) {
                const int m = m0 + wm * 64 + i * 16 + lg * 4 + r;
                const int n = n0 + wn * 64 + j * 16 + lr;
                const float v = acc[i][j][r];
                float vp = 0.f;
                if (MODE == 0 || MODE == 1) vp = __shfl_xor(v, 1);
                if (MODE == 0) {
                    if (n < 1536) {
                        F0[(size_t)m * 1536 + n] = v;
                    } else if (n < 2048) {
                        F1[(size_t)m * 512 + (n - 1536)] = v;
                    } else if (n < 2112) {
                        const int jj = n - 2048;
                        const int fi = jj >> 1;
                        const int spos = m & (SS - 1);
                        const float freq = __expf(-ROPE_C * (float)fi);
                        const float ang = (float)spos * freq;
                        const float sn = __sinf(ang), cs = __cosf(ang);
                        const float o = (jj & 1) ? (vp * sn + v * cs) : (v * cs - vp * sn);
                        B0[(size_t)m * 64 + jj] = (__bf16)o;
                    }
                } else if (MODE == 1) {
                    if (n < 2048) {
                        B0[(size_t)m * 3072 + (n >> 7) * 192 + (n & 127)] = (__bf16)(v * QSCALE);
                    } else {
                        const int jj = n - 2048;
                        const int h = jj >> 6, dd = jj & 63;
                        const int fi = dd >> 1;
                        const int spos = m & (SS - 1);
                        const float freq = __expf(-ROPE_C * (float)fi);
                        const float ang = (float)spos * freq;
                        const float sn = __sinf(ang), cs = __cosf(ang);
                        const float o = (dd & 1) ? (vp * sn + v * cs) : (v * cs - vp * sn);
                        B0[(size_t)m * 3072 + h * 192 + 128 + dd] = (__bf16)(o * QSCALE);
                    }
                } else if (MODE == 2) {
                    const int h = n >> 8, off = n & 255;
                    if (off < 128)
                        B0[(size_t)m * 2048 + h * 128 + off] = (__bf16)v;
                    else
                        B1[(((size_t)(m >> 11) * NHH + h) * 128 + (off - 128)) * SS + (m & (SS - 1))] = (__bf16)v;
                } else {
                    F0[(size_t)m * N + n] = v;
                }
            }
        }
    }
}

// ---------------------------------------------------------------------------
// MFMA flash attention v6: per-wave cross-tile grouping. Wave w owns
// grp0 = rows of tile bx (16) and grp1 = rows of tile 15-bx (16) -> every
// wave active all iterations (2 waves/SIMD overlap), blocks balanced.
// P tile uses rotation layout: Ps[q][ (k + (q>>2)*16) & 63 ], dense 128B
// rows -> conflict-free b64... (store: 64 lanes cover 64 distinct elems);
// b128 reads at the 8-cycle optimum. KV tile 64, double-buffered LDS,
// async reg-staging, XCD-aligned mapping, setprio, defer-max.
// ---------------------------------------------------------------------------
__global__ __launch_bounds__(512, 1) void attn_mfma6(
        const __bf16* __restrict__ q, const __bf16* __restrict__ knope,
        const __bf16* __restrict__ krope, const __bf16* __restrict__ vT,
        __bf16* __restrict__ att) {
    const int flat = blockIdx.x;
    const int xcd = flat & 7;
    const int a0 = flat >> 3;
    const int bx = a0 & 7;
    const int g8 = ((a0 >> 3) << 3) | xcd;
    const int h = g8 & 15;
    const int b = g8 >> 4;

    const int tid = threadIdx.x;
    const int w  = tid >> 6;
    const int l  = tid & 63;
    const int lr = l & 15;
    const int lg = l >> 4;

    __shared__ __bf16 Ks[2][64][200];
    __shared__ __bf16 Vs[2][128][72];
    __shared__ __bf16 Ps[8][2][16][64];    // rotation layout, dense 128B rows

    const int rg[2] = {bx * 128 + w * 16, (15 - bx) * 128 + w * 16};
    const int nkt = 2 * (15 - bx) + 2;

    bf16x8 sreg[5];
    auto stage_load = [&](int kv0) {
#pragma unroll
        for (int i = 0; i < 5; ++i) {
            const int gc = tid + 512 * i;
            if (gc < 1536) {
                const int row = gc / 24, cc = gc - row * 24;
                const size_t tt = (size_t)(b * SS + kv0 + row);
                const __bf16* src = (cc < 16)
                    ? knope + tt * 2048 + h * 128 + cc * 8
                    : krope + tt * 64 + (cc - 16) * 8;
                sreg[i] = *(const bf16x8*)src;
            } else {
                const int c = gc - 1536;
                const int row = c >> 3, cc = c & 7;
                sreg[i] = *(const bf16x8*)(vT + (((size_t)b * NHH + h) * 128 + row) * SS
                                              + kv0 + cc * 8);
            }
        }
    };
    auto stage_write = [&](int bi) {
#pragma unroll
        for (int i = 0; i < 5; ++i) {
            const int gc = tid + 512 * i;
            if (gc < 1536) {
                const int row = gc / 24, cc = gc - row * 24;
                *(bf16x8*)&Ks[bi][row][cc * 8] = sreg[i];
            } else {
                const int c = gc - 1536;
                *(bf16x8*)&Vs[bi][c >> 3][(c & 7) * 8] = sreg[i];
            }
        }
    };

    // Q fragments for both groups
    bf16x8 qf[2][6];
#pragma unroll
    for (int grp = 0; grp < 2; ++grp) {
        const __bf16* qb = q + (((size_t)(b * SS + rg[grp] + lr)) * NHH + h) * DQK + lg * 8;
#pragma unroll
        for (int c = 0; c < 6; ++c) qf[grp][c] = *(const bf16x8*)(qb + c * 32);
    }

    f32x4 O[2][8];
    float m_r[2][4], l_r[2][4];
#pragma unroll
    for (int grp = 0; grp < 2; ++grp) {
#pragma unroll
        for (int n = 0; n < 8; ++n) O[grp][n] = (f32x4){0.f, 0.f, 0.f, 0.f};
#pragma unroll
        for (int r = 0; r < 4; ++r) { m_r[grp][r] = -INFINITY; l_r[grp][r] = 0.f; }
    }

    stage_load(0);
    stage_write(0);
    __syncthreads();
    int cur = 0;

    for (int kt = 0; kt < nkt; ++kt) {
        const int kv0 = kt * 64;
        const bool hasNext = (kt + 1 < nkt);
        if (hasNext) stage_load(kv0 + 64);

        const bool act0 = kv0 <= rg[0] + 15;
        const bool act1 = kv0 <= rg[1] + 15;
        if (act1 || act0) {
            // ---- QK^T: K-frags read once, used by both groups ----
            f32x4 sc[2][4];
#pragma unroll
            for (int s = 0; s < 4; ++s) {
                const int colb = kv0 + s * 16;
                if (colb <= rg[1] + 15 || colb <= rg[0] + 15) {
                    bf16x8 kf[6];
#pragma unroll
                    for (int c = 0; c < 6; ++c)
                        kf[c] = *(const bf16x8*)&Ks[cur][s * 16 + lr][c * 32 + lg * 8];
                    __builtin_amdgcn_s_setprio(1);
#pragma unroll
                    for (int grp = 0; grp < 2; ++grp) {
                        if (colb <= rg[grp] + 15) {
                            f32x4 acc = (f32x4){0.f, 0.f, 0.f, 0.f};
#pragma unroll
                            for (int c = 0; c < 6; ++c)
                                acc = __builtin_amdgcn_mfma_f32_16x16x32_bf16(qf[grp][c], kf[c], acc, 0, 0, 0);
                            sc[grp][s] = acc;
                        } else {
                            sc[grp][s] = (f32x4){-INFINITY, -INFINITY, -INFINITY, -INFINITY};
                        }
                    }
                    __builtin_amdgcn_s_setprio(0);
                } else {
                    sc[0][s] = (f32x4){-INFINITY, -INFINITY, -INFINITY, -INFINITY};
                    sc[1][s] = (f32x4){-INFINITY, -INFINITY, -INFINITY, -INFINITY};
                }
            }

            // ---- softmax per group (defer-max) + rotated P store ----
#pragma unroll
            for (int grp = 0; grp < 2; ++grp) {
                const bool act = (grp == 0) ? act0 : act1;
                if (!act) continue;
                const int rgg = rg[grp];
#pragma unroll
                for (int s = 0; s < 4; ++s) {
                    const int col = kv0 + s * 16 + lr;
#pragma unroll
                    for (int r = 0; r < 4; ++r)
                        if (col > rgg + lg * 4 + r) sc[grp][s][r] = -INFINITY;
                }
                float mt[4];
#pragma unroll
                for (int r = 0; r < 4; ++r) {
                    float m = fmaxf(fmaxf(sc[grp][0][r], sc[grp][1][r]),
                                    fmaxf(sc[grp][2][r], sc[grp][3][r]));
                    m = fmaxf(m, __shfl_xor(m, 1));
                    m = fmaxf(m, __shfl_xor(m, 2));
                    m = fmaxf(m, __shfl_xor(m, 4));
                    m = fmaxf(m, __shfl_xor(m, 8));
                    mt[r] = m;
                }
                const bool ok = (mt[0] <= m_r[grp][0] + 8.f) && (mt[1] <= m_r[grp][1] + 8.f) &&
                                (mt[2] <= m_r[grp][2] + 8.f) && (mt[3] <= m_r[grp][3] + 8.f);
                if (!__all(ok)) {
#pragma unroll
                    for (int r = 0; r < 4; ++r) {
                        const float mn = fmaxf(m_r[grp][r], mt[r]);
                        const float al = __expf(m_r[grp][r] - mn);
                        m_r[grp][r] = mn;
                        l_r[grp][r] *= al;
#pragma unroll
                        for (int n = 0; n < 8; ++n) O[grp][n][r] *= al;
                    }
                }
#pragma unroll
                for (int s = 0; s < 4; ++s) {
#pragma unroll
                    for (int r = 0; r < 4; ++r) {
                        const float pv = __expf(sc[grp][s][r] - m_r[grp][r]);
                        sc[grp][s][r] = pv;
                        // rotation layout: row q = lg*4+r, col (k + (q>>2)*16)&63
                        Ps[w][grp][lg * 4 + r][(s * 16 + lr + lg * 16) & 63] = (__bf16)pv;
                    }
                }
#pragma unroll
                for (int r = 0; r < 4; ++r) {
                    float ls = (sc[grp][0][r] + sc[grp][1][r]) + (sc[grp][2][r] + sc[grp][3][r]);
                    ls += __shfl_xor(ls, 1);
                    ls += __shfl_xor(ls, 2);
                    ls += __shfl_xor(ls, 4);
                    ls += __shfl_xor(ls, 8);
                    l_r[grp][r] += ls;
                }
            }

            // ---- PV: V-frags read once, used by both groups ----
            bf16x8 pf[2][2];
#pragma unroll
            for (int grp = 0; grp < 2; ++grp)
#pragma unroll
                for (int ks = 0; ks < 2; ++ks)
                    pf[grp][ks] = *(const bf16x8*)&Ps[w][grp][lr]
                                      [(ks * 32 + lg * 8 + ((lr >> 2) << 4)) & 63];
#pragma unroll
            for (int n = 0; n < 8; ++n) {
                bf16x8 v0 = *(const bf16x8*)&Vs[cur][n * 16 + lr][lg * 8];
                bf16x8 v1 = *(const bf16x8*)&Vs[cur][n * 16 + lr][32 + lg * 8];
                __builtin_amdgcn_s_setprio(1);
                if (act0) {
                    O[0][n] = __builtin_amdgcn_mfma_f32_16x16x32_bf16(pf[0][0], v0, O[0][n], 0, 0, 0);
                    O[0][n] = __builtin_amdgcn_mfma_f32_16x16x32_bf16(pf[0][1], v1, O[0][n], 0, 0, 0);
                }
                if (act1) {
                    O[1][n] = __builtin_amdgcn_mfma_f32_16x16x32_bf16(pf[1][0], v0, O[1][n], 0, 0, 0);
                    O[1][n] = __builtin_amdgcn_mfma_f32_16x16x32_bf16(pf[1][1], v1, O[1][n], 0, 0, 0);
                }
                __builtin_amdgcn_s_setprio(0);
            }
        }

        if (hasNext) stage_write(cur ^ 1);
        __syncthreads();
        cur ^= 1;
    }

    // ---- epilogue ----
#pragma unroll
    for (int grp = 0; grp < 2; ++grp) {
        float inv[4];
#pragma unroll
        for (int r = 0; r < 4; ++r) inv[r] = 1.0f / l_r[grp][r];
#pragma unroll
        for (int n = 0; n < 8; ++n) {
#pragma unroll
            for (int r = 0; r < 4; ++r) {
                const size_t tt = (size_t)(b * SS + rg[grp] + lg * 4 + r);
                att[(tt * NHH + h) * 128 + n * 16 + lr] = (__bf16)(O[grp][n][r] * inv[r]);
            }
        }
    }
}

// ---------------------------------------------------------------------------
extern "C" void kernel_launch(void* const* d_in, const int* in_sizes, int n_in,
                              void* d_out, int out_size, void* d_ws, size_t ws_size,
                              hipStream_t stream) {
    (void)in_sizes; (void)n_in; (void)out_size; (void)ws_size;
    const float* x        = (const float*)d_in[0];
    const float* wq_down  = (const float*)d_in[1];
    const float* wq_up    = (const float*)d_in[2];
    const float* wq_rope  = (const float*)d_in[3];
    const float* q_norm_w = (const float*)d_in[4];
    const float* wkv_down = (const float*)d_in[5];
    const float* kv_norm_w= (const float*)d_in[6];
    const float* wkv_up   = (const float*)d_in[7];
    const float* wk_rope  = (const float*)d_in[8];
    const float* wo       = (const float*)d_in[9];
    float* out = (float*)d_out;

    char* ws = (char*)d_ws;
    float*  q_c   = (float*)(ws + 0);            // 24MB fp32 [4096][1536]
    __bf16* att   = (__bf16*)(ws + 0);           // 16MB bf16, aliases dead q_c
    float*  kv_c  = (float*)(ws + 25165824);     // 8MB fp32 [4096][512]
    __bf16* xb    = (__bf16*)(ws + 33554432);    // 16MB bf16 [4096][2048]
    __bf16* vT    = (__bf16*)(ws + 33554432);    // 16MB bf16, aliases dead xb
    __bf16* qc_b  = (__bf16*)(ws + 50331648);    // 12MB bf16 [4096][1536]
    __bf16* kvc_b = (__bf16*)(ws + 62914560);    // 4MB bf16 [4096][512]
    __bf16* krope = (__bf16*)(ws + 67108864);    // 0.5MB bf16 [4096][64]
    __bf16* qbuf  = (__bf16*)(ws + 67633152);    // 24MB bf16 [4096][3072]
    __bf16* wqd_b = (__bf16*)(ws + 92798976);    // 6MB
    __bf16* wqu_b = (__bf16*)(ws + 99090432);    // 6MB
    __bf16* wqr_b = (__bf16*)(ws + 105381888);   // 3MB
    __bf16* wkvd_b= (__bf16*)(ws + 108527616);   // 2MB
    __bf16* wkvu_b= (__bf16*)(ws + 110624768);   // 4MB
    __bf16* wkr_b = (__bf16*)(ws + 114819072);   // 0.25MB
    __bf16* wo_b  = (__bf16*)(ws + 115081216);   // 8MB (end 123469824)
    __bf16* knope = (__bf16*)d_out;              // 16MB bf16 in d_out (dead until final GEMM)

    const dim3 blk(256);

    cast_all<<<dim3(SEG7 / 2048), blk, 0, stream>>>(
        x, wq_down, wkv_down, wk_rope, wq_up, wq_rope, wkv_up, wo,
        xb, wqd_b, wkvd_b, wkr_b, wqu_b, wqr_b, wkvu_b, wo_b);

    // X-GEMM: 1-D grid, 256 full tiles + 32 cheap strip tiles last
    gemm8<0><<<dim3(288), dim3(512), 0, stream>>>(xb, wqd_b, wkvd_b, wkr_b,
                                                  q_c, kv_c, krope, nullptr, TT, 2112, 2048);

    rmsnorm_k<<<dim3(TT), blk, 0, stream>>>(q_c, qc_b, q_norm_w, 1536);
    rmsnorm_k<<<dim3(TT), blk, 0, stream>>>(kv_c, kvc_b, kv_norm_w, 512);

    gemm8<1><<<dim3(12, 32), dim3(512), 0, stream>>>(qc_b, wqu_b, wqr_b, nullptr,
                                                     nullptr, nullptr, qbuf, nullptr, TT, 3072, 1536);

    gemm8<2><<<dim3(16, 32), dim3(512), 0, stream>>>(kvc_b, wkvu_b, nullptr, nullptr,
                                                     nullptr, nullptr, knope, vT, TT, 4096, 512);

    attn_mfma6<<<dim3(256), dim3(512), 0, stream>>>(qbuf, knope, krope, vT, att);

    gemm8<3><<<dim3(8, 32), dim3(512), 0, stream>>>(att, wo_b, nullptr, nullptr,
                                                    out, nullptr, nullptr, nullptr, TT, 2048, 2048);
}

// Round 10
// 354.688 us; speedup vs baseline: 1.1664x; 1.0567x over previous
//
#include <hip/hip_runtime.h>
#include <hip/hip_bf16.h>
#include <math.h>

#define NHH 16
#define SS  2048
#define TT  4096            // B*S tokens
#define DQK 192
#define QSCALE 0.07216878364870322f   // 1/sqrt(192)
#define ROPE_C 0.28782313662425574f   // 2*ln(10000)/64

typedef __bf16 bf16x8 __attribute__((ext_vector_type(8)));
typedef float f32x4 __attribute__((ext_vector_type(4)));

#define GLOAD16(gp, lp) __builtin_amdgcn_global_load_lds( \
    (const __attribute__((address_space(1))) void*)(gp),  \
    (__attribute__((address_space(3))) void*)(lp), 16, 0, 0)

// ---------------------------------------------------------------------------
// Fused fp32 -> bf16 cast of x + all 7 weight tensors.
// ---------------------------------------------------------------------------
#define SEG0 8388608     // x
#define SEG1 11534336    // + wq_down (3145728)
#define SEG2 12582912    // + wkv_down (1048576)
#define SEG3 12713984    // + wk_rope (131072)
#define SEG4 15859712    // + wq_up (3145728)
#define SEG5 17432576    // + wq_rope (1572864)
#define SEG6 19529728    // + wkv_up (2097152)
#define SEG7 23724032    // + wo (4194304)

__global__ __launch_bounds__(256) void cast_all(
        const float* __restrict__ x, const float* __restrict__ wqd,
        const float* __restrict__ wkvd, const float* __restrict__ wkr,
        const float* __restrict__ wqu, const float* __restrict__ wqr,
        const float* __restrict__ wkvu, const float* __restrict__ wo,
        __bf16* __restrict__ xb, __bf16* __restrict__ wqd_b,
        __bf16* __restrict__ wkvd_b, __bf16* __restrict__ wkr_b,
        __bf16* __restrict__ wqu_b, __bf16* __restrict__ wqr_b,
        __bf16* __restrict__ wkvu_b, __bf16* __restrict__ wo_b) {
    const int i = (blockIdx.x * 256 + threadIdx.x) * 8;
    const float* src;
    __bf16* dst;
    int off;
    if (i < SEG0)      { src = x;    dst = xb;     off = i; }
    else if (i < SEG1) { src = wqd;  dst = wqd_b;  off = i - SEG0; }
    else if (i < SEG2) { src = wkvd; dst = wkvd_b; off = i - SEG1; }
    else if (i < SEG3) { src = wkr;  dst = wkr_b;  off = i - SEG2; }
    else if (i < SEG4) { src = wqu;  dst = wqu_b;  off = i - SEG3; }
    else if (i < SEG5) { src = wqr;  dst = wqr_b;  off = i - SEG4; }
    else if (i < SEG6) { src = wkvu; dst = wkvu_b; off = i - SEG5; }
    else               { src = wo;   dst = wo_b;   off = i - SEG6; }
    const float4 a = *(const float4*)(src + off);
    const float4 b = *(const float4*)(src + off + 4);
    __bf16 o[8] = {(__bf16)a.x, (__bf16)a.y, (__bf16)a.z, (__bf16)a.w,
                   (__bf16)b.x, (__bf16)b.y, (__bf16)b.z, (__bf16)b.w};
    *(bf16x8*)(dst + off) = *(const bf16x8*)o;
}

// ---------------------------------------------------------------------------
// RMSNorm: fp32 in -> bf16 out
// ---------------------------------------------------------------------------
__global__ __launch_bounds__(256) void rmsnorm_k(const float* __restrict__ in,
                                                 __bf16* __restrict__ out,
                                                 const float* __restrict__ w, int N) {
    const int row = blockIdx.x;
    const float* xr = in + (size_t)row * N;
    float ss = 0.f;
    for (int i = threadIdx.x; i < N; i += 256) {
        float v = xr[i];
        ss += v * v;
    }
    __shared__ float red[256];
    red[threadIdx.x] = ss;
    __syncthreads();
    for (int s = 128; s > 0; s >>= 1) {
        if (threadIdx.x < s) red[threadIdx.x] += red[threadIdx.x + s];
        __syncthreads();
    }
    const float scale = rsqrtf(red[0] / (float)N + 1e-6f);
    __bf16* orow = out + (size_t)row * N;
    for (int i = threadIdx.x; i < N; i += 256) orow[i] = (__bf16)(xr[i] * scale * w[i]);
}

// ---------------------------------------------------------------------------
// bf16 MFMA NT-GEMM v2: ONE barrier + ONE counted vmcnt per K-tile.
// BM=128, BN=256, BK=64, 512 thr (8 waves 2x4), per-wave 64x64; 3-buffer LDS
// pipeline, global_load_lds staging (all 6 issues up front each iter),
// XOR-swizzled LDS (source-inverse + read-swizzle), setprio around MFMA.
// MODE 0: X-GEMM, 1-D grid 288 (256 full + 32 cheap strips at n0=2048).
// MODE 1: fused Q-GEMM (fb<384, A=qc, K=1536) + KV-GEMM (fb>=384, A=kvc,
//         K=512, A via F0, vT via F1, knope via B1).
// MODE 3: O-GEMM, 2-D grid, plain fp32 out.
// ---------------------------------------------------------------------------
template<int MODE>
__global__ __launch_bounds__(512, 1) void gemm9(
        const __bf16* __restrict__ A,
        const __bf16* __restrict__ W0, const __bf16* __restrict__ W1,
        const __bf16* __restrict__ W2,
        float* __restrict__ F0, float* __restrict__ F1,
        __bf16* __restrict__ B0, __bf16* __restrict__ B1,
        int M, int N, int Kin) {
    __shared__ __bf16 lds[3 * 24576];
    const int tid = threadIdx.x;
    const int w = tid >> 6, l = tid & 63;
    const int lr = l & 15, lg = l >> 4;
    const int wm = w >> 2, wn = w & 3;

    int m0, n0, nlim = 256, K = Kin;
    bool isKV = false;
    const __bf16* Ause = A;
    if (MODE == 0) {
        const int fb = blockIdx.x;
        if (fb < 256) { m0 = (fb >> 3) * 128; n0 = (fb & 7) * 256; }
        else          { m0 = (fb - 256) * 128; n0 = 2048; }
        nlim = 2112 - n0;
    } else if (MODE == 1) {
        int fb = blockIdx.x;
        isKV = (fb >= 384);
        if (isKV) { fb -= 384; K = 512; Ause = (const __bf16*)F0; }
        m0 = (fb & 31) * 128;
        n0 = (fb >> 5) * 256;
    } else {
        m0 = blockIdx.y * 128; n0 = blockIdx.x * 256;
    }
    const bool fullB = (nlim >= 256);
    const bool wAct  = (wn * 64 < nlim);

    const int srow = (w << 3) + (l >> 3);
    const int scol = (l & 7) << 3;
    const int sswz = ((srow >> 1) & 7) << 3;
    const int csw  = scol ^ sswz;

    const __bf16* aptr[2];
#pragma unroll
    for (int a = 0; a < 2; ++a)
        aptr[a] = Ause + (size_t)(m0 + a * 64 + srow) * K + csw;

    const __bf16* bptr[4];
#pragma unroll
    for (int bb = 0; bb < 4; ++bb) {
        const int n = n0 + bb * 64 + srow;
        const __bf16* wp;
        if (MODE == 0) {
            if (n < 1536)      wp = W0 + (size_t)n * K;
            else if (n < 2048) wp = W1 + (size_t)(n - 1536) * K;
            else if (n < 2112) wp = W2 + (size_t)(n - 2048) * K;
            else               wp = W0;
        } else if (MODE == 1) {
            if (isKV)          wp = W2 + (size_t)n * K;
            else               wp = (n < 2048) ? W0 + (size_t)n * K
                                               : W1 + (size_t)(n - 2048) * K;
        } else {
            wp = W0 + (size_t)n * K;
        }
        bptr[bb] = wp + csw;
    }

    auto stA = [&](int t2, int a) {
        GLOAD16(aptr[a] + (size_t)t2 * 64,
                &lds[(t2 % 3) * 24576 + a * 4096 + tid * 8]);
    };
    auto stB = [&](int t2, int b) {
        GLOAD16(bptr[b] + (size_t)t2 * 64,
                &lds[(t2 % 3) * 24576 + 8192 + b * 4096 + tid * 8]);
    };

    const int rswz = ((lr >> 1) & 7) << 3;

    f32x4 acc[4][4];
#pragma unroll
    for (int i = 0; i < 4; ++i)
#pragma unroll
        for (int j = 0; j < 4; ++j) acc[i][j] = (f32x4){0.f, 0.f, 0.f, 0.f};

    const int NT = K >> 6;
#pragma unroll
    for (int t = 0; t < 2; ++t) {
        stA(t, 0); stA(t, 1);
        stB(t, 0);
        if (fullB) { stB(t, 1); stB(t, 2); stB(t, 3); }
    }

    for (int t = 0; t < NT; ++t) {
        if (t + 1 < NT) {
            if (fullB) asm volatile("s_waitcnt vmcnt(6)" ::: "memory");
            else       asm volatile("s_waitcnt vmcnt(3)" ::: "memory");
        } else {
            asm volatile("s_waitcnt vmcnt(0)" ::: "memory");
        }
        __builtin_amdgcn_s_barrier();

        const __bf16* As_ = &lds[(t % 3) * 24576];
        const __bf16* Bs_ = As_ + 8192;

        // issue all next-next-tile stages first (loads fly under compute)
        if (t + 2 < NT) {
            const int t2 = t + 2;
            stA(t2, 0); stA(t2, 1);
            stB(t2, 0);
            if (fullB) { stB(t2, 1); stB(t2, 2); stB(t2, 3); }
        }

        if (wAct) {
            bf16x8 fa[4][2], fb[4][2];
#pragma unroll
            for (int i = 0; i < 4; ++i)
#pragma unroll
                for (int kk = 0; kk < 2; ++kk)
                    fa[i][kk] = *(const bf16x8*)&As_[(wm * 64 + i * 16 + lr) * 64 +
                                                     ((kk * 32 + lg * 8) ^ rswz)];
#pragma unroll
            for (int j = 0; j < 4; ++j)
#pragma unroll
                for (int kk = 0; kk < 2; ++kk)
                    fb[j][kk] = *(const bf16x8*)&Bs_[(wn * 64 + j * 16 + lr) * 64 +
                                                     ((kk * 32 + lg * 8) ^ rswz)];
            __builtin_amdgcn_s_setprio(1);
#pragma unroll
            for (int i = 0; i < 4; ++i)
#pragma unroll
                for (int j = 0; j < 4; ++j)
#pragma unroll
                    for (int kk = 0; kk < 2; ++kk)
                        acc[i][j] = __builtin_amdgcn_mfma_f32_16x16x32_bf16(fa[i][kk], fb[j][kk], acc[i][j], 0, 0, 0);
            __builtin_amdgcn_s_setprio(0);
        }
    }

    if (!wAct) return;

    // ---- epilogue: m = m0+wm*64+i*16+lg*4+r, n = n0+wn*64+j*16+lr ----
#pragma unroll
    for (int i = 0; i < 4; ++i) {
#pragma unroll
        for (int j = 0; j < 4; ++j) {
#pragma unroll
            for (int r = 0; r < 4; ++r) {
                const int m = m0 + wm * 64 + i * 16 + lg * 4 + r;
                const int n = n0 + wn * 64 + j * 16 + lr;
                const float v = acc[i][j][r];
                float vp = 0.f;
                if (MODE == 0 || MODE == 1) vp = __shfl_xor(v, 1);  // rope partner
                if (MODE == 0) {
                    if (n < 1536) {
                        F0[(size_t)m * 1536 + n] = v;
                    } else if (n < 2048) {
                        F1[(size_t)m * 512 + (n - 1536)] = v;
                    } else if (n < 2112) {
                        const int jj = n - 2048;
                        const int fi = jj >> 1;
                        const int spos = m & (SS - 1);
                        const float freq = __expf(-ROPE_C * (float)fi);
                        const float ang = (float)spos * freq;
                        const float sn = __sinf(ang), cs = __cosf(ang);
                        const float o = (jj & 1) ? (vp * sn + v * cs) : (v * cs - vp * sn);
                        B0[(size_t)m * 64 + jj] = (__bf16)o;
                    }
                } else if (MODE == 1) {
                    if (!isKV) {
                        if (n < 2048) {
                            B0[(size_t)m * 3072 + (n >> 7) * 192 + (n & 127)] = (__bf16)(v * QSCALE);
                        } else {
                            const int jj = n - 2048;
                            const int h = jj >> 6, dd = jj & 63;
                            const int fi = dd >> 1;
                            const int spos = m & (SS - 1);
                            const float freq = __expf(-ROPE_C * (float)fi);
                            const float ang = (float)spos * freq;
                            const float sn = __sinf(ang), cs = __cosf(ang);
                            const float o = (dd & 1) ? (vp * sn + v * cs) : (v * cs - vp * sn);
                            B0[(size_t)m * 3072 + h * 192 + 128 + dd] = (__bf16)(o * QSCALE);
                        }
                    } else {
                        __bf16* vTo = (__bf16*)F1;
                        const int h = n >> 8, off = n & 255;
                        if (off < 128)
                            B1[(size_t)m * 2048 + h * 128 + off] = (__bf16)v;
                        else
                            vTo[(((size_t)(m >> 11) * NHH + h) * 128 + (off - 128)) * SS + (m & (SS - 1))] = (__bf16)v;
                    }
                } else {
                    F0[(size_t)m * N + n] = v;
                }
            }
        }
    }
}

// ---------------------------------------------------------------------------
// MFMA flash attention v7: R9's cross-tile wave grouping (balanced, all waves
// active) + R8's proven pitch-72 P layout (2-way free on store AND b128 read).
// ---------------------------------------------------------------------------
__global__ __launch_bounds__(512, 1) void attn_mfma7(
        const __bf16* __restrict__ q, const __bf16* __restrict__ knope,
        const __bf16* __restrict__ krope, const __bf16* __restrict__ vT,
        __bf16* __restrict__ att) {
    const int flat = blockIdx.x;
    const int xcd = flat & 7;
    const int a0 = flat >> 3;
    const int bx = a0 & 7;
    const int g8 = ((a0 >> 3) << 3) | xcd;
    const int h = g8 & 15;
    const int b = g8 >> 4;

    const int tid = threadIdx.x;
    const int w  = tid >> 6;
    const int l  = tid & 63;
    const int lr = l & 15;
    const int lg = l >> 4;

    __shared__ __bf16 Ks[2][64][200];
    __shared__ __bf16 Vs[2][128][72];
    __shared__ __bf16 Ps[8][2][16][72];

    const int rg[2] = {bx * 128 + w * 16, (15 - bx) * 128 + w * 16};
    const int nkt = 2 * (15 - bx) + 2;

    bf16x8 sreg[5];
    auto stage_load = [&](int kv0) {
#pragma unroll
        for (int i = 0; i < 5; ++i) {
            const int gc = tid + 512 * i;
            if (gc < 1536) {
                const int row = gc / 24, cc = gc - row * 24;
                const size_t tt = (size_t)(b * SS + kv0 + row);
                const __bf16* src = (cc < 16)
                    ? knope + tt * 2048 + h * 128 + cc * 8
                    : krope + tt * 64 + (cc - 16) * 8;
                sreg[i] = *(const bf16x8*)src;
            } else {
                const int c = gc - 1536;
                const int row = c >> 3, cc = c & 7;
                sreg[i] = *(const bf16x8*)(vT + (((size_t)b * NHH + h) * 128 + row) * SS
                                              + kv0 + cc * 8);
            }
        }
    };
    auto stage_write = [&](int bi) {
#pragma unroll
        for (int i = 0; i < 5; ++i) {
            const int gc = tid + 512 * i;
            if (gc < 1536) {
                const int row = gc / 24, cc = gc - row * 24;
                *(bf16x8*)&Ks[bi][row][cc * 8] = sreg[i];
            } else {
                const int c = gc - 1536;
                *(bf16x8*)&Vs[bi][c >> 3][(c & 7) * 8] = sreg[i];
            }
        }
    };

    bf16x8 qf[2][6];
#pragma unroll
    for (int grp = 0; grp < 2; ++grp) {
        const __bf16* qb = q + (((size_t)(b * SS + rg[grp] + lr)) * NHH + h) * DQK + lg * 8;
#pragma unroll
        for (int c = 0; c < 6; ++c) qf[grp][c] = *(const bf16x8*)(qb + c * 32);
    }

    f32x4 O[2][8];
    float m_r[2][4], l_r[2][4];
#pragma unroll
    for (int grp = 0; grp < 2; ++grp) {
#pragma unroll
        for (int n = 0; n < 8; ++n) O[grp][n] = (f32x4){0.f, 0.f, 0.f, 0.f};
#pragma unroll
        for (int r = 0; r < 4; ++r) { m_r[grp][r] = -INFINITY; l_r[grp][r] = 0.f; }
    }

    stage_load(0);
    stage_write(0);
    __syncthreads();
    int cur = 0;

    for (int kt = 0; kt < nkt; ++kt) {
        const int kv0 = kt * 64;
        const bool hasNext = (kt + 1 < nkt);
        if (hasNext) stage_load(kv0 + 64);

        const bool act0 = kv0 <= rg[0] + 15;
        const bool act1 = kv0 <= rg[1] + 15;
        if (act1 || act0) {
            // ---- QK^T: K-frags read once, used by both groups ----
            f32x4 sc[2][4];
#pragma unroll
            for (int s = 0; s < 4; ++s) {
                const int colb = kv0 + s * 16;
                if (colb <= rg[1] + 15 || colb <= rg[0] + 15) {
                    bf16x8 kf[6];
#pragma unroll
                    for (int c = 0; c < 6; ++c)
                        kf[c] = *(const bf16x8*)&Ks[cur][s * 16 + lr][c * 32 + lg * 8];
                    __builtin_amdgcn_s_setprio(1);
#pragma unroll
                    for (int grp = 0; grp < 2; ++grp) {
                        if (colb <= rg[grp] + 15) {
                            f32x4 acc = (f32x4){0.f, 0.f, 0.f, 0.f};
#pragma unroll
                            for (int c = 0; c < 6; ++c)
                                acc = __builtin_amdgcn_mfma_f32_16x16x32_bf16(qf[grp][c], kf[c], acc, 0, 0, 0);
                            sc[grp][s] = acc;
                        } else {
                            sc[grp][s] = (f32x4){-INFINITY, -INFINITY, -INFINITY, -INFINITY};
                        }
                    }
                    __builtin_amdgcn_s_setprio(0);
                } else {
                    sc[0][s] = (f32x4){-INFINITY, -INFINITY, -INFINITY, -INFINITY};
                    sc[1][s] = (f32x4){-INFINITY, -INFINITY, -INFINITY, -INFINITY};
                }
            }

            // ---- softmax per group (defer-max) ----
#pragma unroll
            for (int grp = 0; grp < 2; ++grp) {
                const bool act = (grp == 0) ? act0 : act1;
                if (!act) continue;
                const int rgg = rg[grp];
#pragma unroll
                for (int s = 0; s < 4; ++s) {
                    const int col = kv0 + s * 16 + lr;
#pragma unroll
                    for (int r = 0; r < 4; ++r)
                        if (col > rgg + lg * 4 + r) sc[grp][s][r] = -INFINITY;
                }
                float mt[4];
#pragma unroll
                for (int r = 0; r < 4; ++r) {
                    float m = fmaxf(fmaxf(sc[grp][0][r], sc[grp][1][r]),
                                    fmaxf(sc[grp][2][r], sc[grp][3][r]));
                    m = fmaxf(m, __shfl_xor(m, 1));
                    m = fmaxf(m, __shfl_xor(m, 2));
                    m = fmaxf(m, __shfl_xor(m, 4));
                    m = fmaxf(m, __shfl_xor(m, 8));
                    mt[r] = m;
                }
                const bool ok = (mt[0] <= m_r[grp][0] + 8.f) && (mt[1] <= m_r[grp][1] + 8.f) &&
                                (mt[2] <= m_r[grp][2] + 8.f) && (mt[3] <= m_r[grp][3] + 8.f);
                if (!__all(ok)) {
#pragma unroll
                    for (int r = 0; r < 4; ++r) {
                        const float mn = fmaxf(m_r[grp][r], mt[r]);
                        const float al = __expf(m_r[grp][r] - mn);
                        m_r[grp][r] = mn;
                        l_r[grp][r] *= al;
#pragma unroll
                        for (int n = 0; n < 8; ++n) O[grp][n][r] *= al;
                    }
                }
#pragma unroll
                for (int s = 0; s < 4; ++s) {
#pragma unroll
                    for (int r = 0; r < 4; ++r) {
                        const float pv = __expf(sc[grp][s][r] - m_r[grp][r]);
                        sc[grp][s][r] = pv;
                        Ps[w][grp][lg * 4 + r][s * 16 + lr] = (__bf16)pv;
                    }
                }
#pragma unroll
                for (int r = 0; r < 4; ++r) {
                    float ls = (sc[grp][0][r] + sc[grp][1][r]) + (sc[grp][2][r] + sc[grp][3][r]);
                    ls += __shfl_xor(ls, 1);
                    ls += __shfl_xor(ls, 2);
                    ls += __shfl_xor(ls, 4);
                    ls += __shfl_xor(ls, 8);
                    l_r[grp][r] += ls;
                }
            }

            // ---- PV: V-frags read once, used by both groups ----
            bf16x8 pf[2][2];
#pragma unroll
            for (int grp = 0; grp < 2; ++grp)
#pragma unroll
                for (int ks = 0; ks < 2; ++ks)
                    pf[grp][ks] = *(const bf16x8*)&Ps[w][grp][lr][ks * 32 + lg * 8];
#pragma unroll
            for (int n = 0; n < 8; ++n) {
                bf16x8 v0 = *(const bf16x8*)&Vs[cur][n * 16 + lr][lg * 8];
                bf16x8 v1 = *(const bf16x8*)&Vs[cur][n * 16 + lr][32 + lg * 8];
                __builtin_amdgcn_s_setprio(1);
                if (act0) {
                    O[0][n] = __builtin_amdgcn_mfma_f32_16x16x32_bf16(pf[0][0], v0, O[0][n], 0, 0, 0);
                    O[0][n] = __builtin_amdgcn_mfma_f32_16x16x32_bf16(pf[0][1], v1, O[0][n], 0, 0, 0);
                }
                if (act1) {
                    O[1][n] = __builtin_amdgcn_mfma_f32_16x16x32_bf16(pf[1][0], v0, O[1][n], 0, 0, 0);
                    O[1][n] = __builtin_amdgcn_mfma_f32_16x16x32_bf16(pf[1][1], v1, O[1][n], 0, 0, 0);
                }
                __builtin_amdgcn_s_setprio(0);
            }
        }

        if (hasNext) stage_write(cur ^ 1);
        __syncthreads();
        cur ^= 1;
    }

    // ---- epilogue ----
#pragma unroll
    for (int grp = 0; grp < 2; ++grp) {
        float inv[4];
#pragma unroll
        for (int r = 0; r < 4; ++r) inv[r] = 1.0f / l_r[grp][r];
#pragma unroll
        for (int n = 0; n < 8; ++n) {
#pragma unroll
            for (int r = 0; r < 4; ++r) {
                const size_t tt = (size_t)(b * SS + rg[grp] + lg * 4 + r);
                att[(tt * NHH + h) * 128 + n * 16 + lr] = (__bf16)(O[grp][n][r] * inv[r]);
            }
        }
    }
}

// ---------------------------------------------------------------------------
extern "C" void kernel_launch(void* const* d_in, const int* in_sizes, int n_in,
                              void* d_out, int out_size, void* d_ws, size_t ws_size,
                              hipStream_t stream) {
    (void)in_sizes; (void)n_in; (void)out_size; (void)ws_size;
    const float* x        = (const float*)d_in[0];
    const float* wq_down  = (const float*)d_in[1];
    const float* wq_up    = (const float*)d_in[2];
    const float* wq_rope  = (const float*)d_in[3];
    const float* q_norm_w = (const float*)d_in[4];
    const float* wkv_down = (const float*)d_in[5];
    const float* kv_norm_w= (const float*)d_in[6];
    const float* wkv_up   = (const float*)d_in[7];
    const float* wk_rope  = (const float*)d_in[8];
    const float* wo       = (const float*)d_in[9];
    float* out = (float*)d_out;

    char* ws = (char*)d_ws;
    float*  q_c   = (float*)(ws + 0);            // 24MB fp32 [4096][1536]
    __bf16* att   = (__bf16*)(ws + 0);           // 16MB bf16, aliases dead q_c
    float*  kv_c  = (float*)(ws + 25165824);     // 8MB fp32 [4096][512]
    __bf16* xb    = (__bf16*)(ws + 33554432);    // 16MB bf16 [4096][2048]
    __bf16* vT    = (__bf16*)(ws + 33554432);    // 16MB bf16, aliases dead xb
    __bf16* qc_b  = (__bf16*)(ws + 50331648);    // 12MB bf16 [4096][1536]
    __bf16* kvc_b = (__bf16*)(ws + 62914560);    // 4MB bf16 [4096][512]
    __bf16* krope = (__bf16*)(ws + 67108864);    // 0.5MB bf16 [4096][64]
    __bf16* qbuf  = (__bf16*)(ws + 67633152);    // 24MB bf16 [4096][3072]
    __bf16* wqd_b = (__bf16*)(ws + 92798976);    // 6MB
    __bf16* wqu_b = (__bf16*)(ws + 99090432);    // 6MB
    __bf16* wqr_b = (__bf16*)(ws + 105381888);   // 3MB
    __bf16* wkvd_b= (__bf16*)(ws + 108527616);   // 2MB
    __bf16* wkvu_b= (__bf16*)(ws + 110624768);   // 4MB
    __bf16* wkr_b = (__bf16*)(ws + 114819072);   // 0.25MB
    __bf16* wo_b  = (__bf16*)(ws + 115081216);   // 8MB (end 123469824)
    __bf16* knope = (__bf16*)d_out;              // 16MB bf16 in d_out (dead until final GEMM)

    const dim3 blk(256);

    cast_all<<<dim3(SEG7 / 2048), blk, 0, stream>>>(
        x, wq_down, wkv_down, wk_rope, wq_up, wq_rope, wkv_up, wo,
        xb, wqd_b, wkvd_b, wkr_b, wqu_b, wqr_b, wkvu_b, wo_b);

    // X-GEMM: 256 full tiles + 32 cheap strip tiles
    gemm9<0><<<dim3(288), dim3(512), 0, stream>>>(xb, wqd_b, wkvd_b, wkr_b,
                                                  q_c, kv_c, krope, nullptr, TT, 2112, 2048);

    rmsnorm_k<<<dim3(TT), blk, 0, stream>>>(q_c, qc_b, q_norm_w, 1536);
    rmsnorm_k<<<dim3(TT), blk, 0, stream>>>(kv_c, kvc_b, kv_norm_w, 512);

    // fused Q-GEMM (384 tiles) + KV-GEMM (512 tiles) in one 896-block launch
    gemm9<1><<<dim3(896), dim3(512), 0, stream>>>(qc_b, wqu_b, wqr_b, wkvu_b,
                                                  (float*)kvc_b, (float*)vT,
                                                  qbuf, knope, TT, 3072, 1536);

    attn_mfma7<<<dim3(256), dim3(512), 0, stream>>>(qbuf, knope, krope, vT, att);

    gemm9<3><<<dim3(8, 32), dim3(512), 0, stream>>>(att, wo_b, nullptr, nullptr,
                                                    out, nullptr, nullptr, nullptr, TT, 2048, 2048);
}

// Round 13
// 322.123 us; speedup vs baseline: 1.2844x; 1.1011x over previous
//
#include <hip/hip_runtime.h>
#include <hip/hip_bf16.h>
#include <math.h>

#define NHH 16
#define SS  2048
#define TT  4096            // B*S tokens
#define DQK 192
#define QSCALE 0.07216878364870322f   // 1/sqrt(192)
#define ROPE_C 0.28782313662425574f   // 2*ln(10000)/64

typedef __bf16 bf16x8 __attribute__((ext_vector_type(8)));
typedef float f32x4 __attribute__((ext_vector_type(4)));

#define GLOAD16(gp, lp) __builtin_amdgcn_global_load_lds( \
    (const __attribute__((address_space(1))) void*)(gp),  \
    (__attribute__((address_space(3))) void*)(lp), 16, 0, 0)

// ---------------------------------------------------------------------------
// Fused fp32 -> bf16 cast of x + all 7 weight tensors.
// ---------------------------------------------------------------------------
#define SEG0 8388608     // x
#define SEG1 11534336    // + wq_down (3145728)
#define SEG2 12582912    // + wkv_down (1048576)
#define SEG3 12713984    // + wk_rope (131072)
#define SEG4 15859712    // + wq_up (3145728)
#define SEG5 17432576    // + wq_rope (1572864)
#define SEG6 19529728    // + wkv_up (2097152)
#define SEG7 23724032    // + wo (4194304)

__global__ __launch_bounds__(256) void cast_all(
        const float* __restrict__ x, const float* __restrict__ wqd,
        const float* __restrict__ wkvd, const float* __restrict__ wkr,
        const float* __restrict__ wqu, const float* __restrict__ wqr,
        const float* __restrict__ wkvu, const float* __restrict__ wo,
        __bf16* __restrict__ xb, __bf16* __restrict__ wqd_b,
        __bf16* __restrict__ wkvd_b, __bf16* __restrict__ wkr_b,
        __bf16* __restrict__ wqu_b, __bf16* __restrict__ wqr_b,
        __bf16* __restrict__ wkvu_b, __bf16* __restrict__ wo_b) {
    const int i = (blockIdx.x * 256 + threadIdx.x) * 8;
    const float* src;
    __bf16* dst;
    int off;
    if (i < SEG0)      { src = x;    dst = xb;     off = i; }
    else if (i < SEG1) { src = wqd;  dst = wqd_b;  off = i - SEG0; }
    else if (i < SEG2) { src = wkvd; dst = wkvd_b; off = i - SEG1; }
    else if (i < SEG3) { src = wkr;  dst = wkr_b;  off = i - SEG2; }
    else if (i < SEG4) { src = wqu;  dst = wqu_b;  off = i - SEG3; }
    else if (i < SEG5) { src = wqr;  dst = wqr_b;  off = i - SEG4; }
    else if (i < SEG6) { src = wkvu; dst = wkvu_b; off = i - SEG5; }
    else               { src = wo;   dst = wo_b;   off = i - SEG6; }
    const float4 a = *(const float4*)(src + off);
    const float4 b = *(const float4*)(src + off + 4);
    __bf16 o[8] = {(__bf16)a.x, (__bf16)a.y, (__bf16)a.z, (__bf16)a.w,
                   (__bf16)b.x, (__bf16)b.y, (__bf16)b.z, (__bf16)b.w};
    *(bf16x8*)(dst + off) = *(const bf16x8*)o;
}

// ---------------------------------------------------------------------------
// RMSNorm: fp32 in -> bf16 out
// ---------------------------------------------------------------------------
__global__ __launch_bounds__(256) void rmsnorm_k(const float* __restrict__ in,
                                                 __bf16* __restrict__ out,
                                                 const float* __restrict__ w, int N) {
    const int row = blockIdx.x;
    const float* xr = in + (size_t)row * N;
    float ss = 0.f;
    for (int i = threadIdx.x; i < N; i += 256) {
        float v = xr[i];
        ss += v * v;
    }
    __shared__ float red[256];
    red[threadIdx.x] = ss;
    __syncthreads();
    for (int s = 128; s > 0; s >>= 1) {
        if (threadIdx.x < s) red[threadIdx.x] += red[threadIdx.x + s];
        __syncthreads();
    }
    const float scale = rsqrtf(red[0] / (float)N + 1e-6f);
    __bf16* orow = out + (size_t)row * N;
    for (int i = threadIdx.x; i < N; i += 256) orow[i] = (__bf16)(xr[i] * scale * w[i]);
}

// ---------------------------------------------------------------------------
// bf16 MFMA NT-GEMM v3: BK=32, 3-buffer LDS pipeline at 72KB -> 2 blocks/CU.
// ONE barrier + ONE counted vmcnt per K-tile (prefetch depth 2, never drain
// in steady state). XOR-swizzled LDS (source-inverse + read-swizzle, 4 slots
// of 8 elems per 32-col row). setprio around MFMA cluster.
// MODE 0: X-GEMM, 1-D grid 288 (256 full + 32 cheap strips at n0=2048).
// MODE 1: fused Q-GEMM (fb<384, A=qc, K=1536) + KV-GEMM (fb>=384, A=kvc via
//         F0, K=512, vT via F1, knope via B1).
// MODE 3: O-GEMM, 2-D grid, plain fp32 out.
// ---------------------------------------------------------------------------
template<int MODE>
__global__ __launch_bounds__(512, 2) void gemm10(
        const __bf16* __restrict__ A,
        const __bf16* __restrict__ W0, const __bf16* __restrict__ W1,
        const __bf16* __restrict__ W2,
        float* __restrict__ F0, float* __restrict__ F1,
        __bf16* __restrict__ B0, __bf16* __restrict__ B1,
        int M, int N, int Kin) {
    __shared__ __bf16 lds[3 * 12288];   // 3 x (A 128x32 + B 256x32) = 72KB
    const int tid = threadIdx.x;
    const int w = tid >> 6, l = tid & 63;
    const int lr = l & 15, lg = l >> 4;
    const int wm = w >> 2, wn = w & 3;

    int m0, n0, nlim = 256, K = Kin;
    bool isKV = false;
    const __bf16* Ause = A;
    if (MODE == 0) {
        const int fb = blockIdx.x;
        if (fb < 256) { m0 = (fb >> 3) * 128; n0 = (fb & 7) * 256; }
        else          { m0 = (fb - 256) * 128; n0 = 2048; }
        nlim = 2112 - n0;
    } else if (MODE == 1) {
        int fb = blockIdx.x;
        isKV = (fb >= 384);
        if (isKV) { fb -= 384; K = 512; Ause = (const __bf16*)F0; }
        m0 = (fb & 31) * 128;
        n0 = (fb >> 5) * 256;
    } else {
        m0 = blockIdx.y * 128; n0 = blockIdx.x * 256;
    }
    const bool fullB = (nlim >= 256);
    const bool wAct  = (wn * 64 < nlim);

    // staging geometry: thread covers (row = srow [+128 for B issue 1], col scol)
    const int srow = tid >> 2;              // 0..127
    const int scol = (tid & 3) << 3;        // 0,8,16,24
    const int csw  = scol ^ (((srow >> 1) & 3) << 3);   // inverse-swizzled source col

    const __bf16* aptr = Ause + (size_t)(m0 + srow) * K + csw;

    const __bf16* bptr[2];
#pragma unroll
    for (int i = 0; i < 2; ++i) {
        const int row = i * 128 + srow;
        const int n = n0 + row;
        const __bf16* wp;
        if (MODE == 0) {
            if (n < 1536)      wp = W0 + (size_t)n * K;
            else if (n < 2048) wp = W1 + (size_t)(n - 1536) * K;
            else if (n < 2112) wp = W2 + (size_t)(n - 2048) * K;
            else               wp = W0;                 // clamp (never read)
        } else if (MODE == 1) {
            if (isKV)          wp = W2 + (size_t)n * K;
            else               wp = (n < 2048) ? W0 + (size_t)n * K
                                               : W1 + (size_t)(n - 2048) * K;
        } else {
            wp = W0 + (size_t)n * K;
        }
        bptr[i] = wp + csw;
    }

    auto stA = [&](int t2) {
        GLOAD16(aptr + (size_t)t2 * 32, &lds[(t2 % 3) * 12288 + tid * 8]);
    };
    auto stB = [&](int t2, int i) {
        GLOAD16(bptr[i] + (size_t)t2 * 32,
                &lds[(t2 % 3) * 12288 + 4096 + i * 4096 + tid * 8]);
    };

    const int rswz = ((lr >> 1) & 3) << 3;

    f32x4 acc[4][4];
#pragma unroll
    for (int i = 0; i < 4; ++i)
#pragma unroll
        for (int j = 0; j < 4; ++j) acc[i][j] = (f32x4){0.f, 0.f, 0.f, 0.f};

    const int NT = K >> 5;
    stA(0); stB(0, 0); if (fullB) stB(0, 1);
    stA(1); stB(1, 0); if (fullB) stB(1, 1);

    for (int t = 0; t < NT; ++t) {
        if (t + 1 < NT) {
            if (fullB) asm volatile("s_waitcnt vmcnt(3)" ::: "memory");
            else       asm volatile("s_waitcnt vmcnt(2)" ::: "memory");
        } else {
            asm volatile("s_waitcnt vmcnt(0)" ::: "memory");
        }
        __builtin_amdgcn_s_barrier();

        const __bf16* As_ = &lds[(t % 3) * 12288];
        const __bf16* Bs_ = As_ + 4096;

        if (t + 2 < NT) {                  // issue next-next-tile stages first
            stA(t + 2); stB(t + 2, 0); if (fullB) stB(t + 2, 1);
        }

        if (wAct) {
            bf16x8 fa[4], fb[4];
#pragma unroll
            for (int i = 0; i < 4; ++i)
                fa[i] = *(const bf16x8*)&As_[(wm * 64 + i * 16 + lr) * 32 +
                                             ((lg * 8) ^ rswz)];
#pragma unroll
            for (int j = 0; j < 4; ++j)
                fb[j] = *(const bf16x8*)&Bs_[(wn * 64 + j * 16 + lr) * 32 +
                                             ((lg * 8) ^ rswz)];
            __builtin_amdgcn_s_setprio(1);
#pragma unroll
            for (int i = 0; i < 4; ++i)
#pragma unroll
                for (int j = 0; j < 4; ++j)
                    acc[i][j] = __builtin_amdgcn_mfma_f32_16x16x32_bf16(fa[i], fb[j], acc[i][j], 0, 0, 0);
            __builtin_amdgcn_s_setprio(0);
        }
    }

    if (!wAct) return;

    // ---- epilogue: m = m0+wm*64+i*16+lg*4+r, n = n0+wn*64+j*16+lr ----
#pragma unroll
    for (int i = 0; i < 4; ++i) {
#pragma unroll
        for (int j = 0; j < 4; ++j) {
#pragma unroll
            for (int r = 0; r < 4; ++r) {
                const int m = m0 + wm * 64 + i * 16 + lg * 4 + r;
                const int n = n0 + wn * 64 + j * 16 + lr;
                const float v = acc[i][j][r];
                float vp = 0.f;
                if (MODE == 0 || MODE == 1) vp = __shfl_xor(v, 1);  // rope partner
                if (MODE == 0) {
                    if (n < 1536) {
                        F0[(size_t)m * 1536 + n] = v;
                    } else if (n < 2048) {
                        F1[(size_t)m * 512 + (n - 1536)] = v;
                    } else if (n < 2112) {
                        const int jj = n - 2048;
                        const int fi = jj >> 1;
                        const int spos = m & (SS - 1);
                        const float freq = __expf(-ROPE_C * (float)fi);
                        const float ang = (float)spos * freq;
                        const float sn = __sinf(ang), cs = __cosf(ang);
                        const float o = (jj & 1) ? (vp * sn + v * cs) : (v * cs - vp * sn);
                        B0[(size_t)m * 64 + jj] = (__bf16)o;
                    }
                } else if (MODE == 1) {
                    if (!isKV) {
                        if (n < 2048) {
                            B0[(size_t)m * 3072 + (n >> 7) * 192 + (n & 127)] = (__bf16)(v * QSCALE);
                        } else {
                            const int jj = n - 2048;
                            const int h = jj >> 6, dd = jj & 63;
                            const int fi = dd >> 1;
                            const int spos = m & (SS - 1);
                            const float freq = __expf(-ROPE_C * (float)fi);
                            const float ang = (float)spos * freq;
                            const float sn = __sinf(ang), cs = __cosf(ang);
                            const float o = (dd & 1) ? (vp * sn + v * cs) : (v * cs - vp * sn);
                            B0[(size_t)m * 3072 + h * 192 + 128 + dd] = (__bf16)(o * QSCALE);
                        }
                    } else {
                        __bf16* vTo = (__bf16*)F1;
                        const int h = n >> 8, off = n & 255;
                        if (off < 128)
                            B1[(size_t)m * 2048 + h * 128 + off] = (__bf16)v;
                        else
                            vTo[(((size_t)(m >> 11) * NHH + h) * 128 + (off - 128)) * SS + (m & (SS - 1))] = (__bf16)v;
                    }
                } else {
                    F0[(size_t)m * N + n] = v;
                }
            }
        }
    }
}

// ---------------------------------------------------------------------------
// MFMA flash attention v7 (R10-passing version, reverted verbatim):
// cross-tile wave grouping + pitch-72 P layout.
// ---------------------------------------------------------------------------
__global__ __launch_bounds__(512, 1) void attn_mfma7(
        const __bf16* __restrict__ q, const __bf16* __restrict__ knope,
        const __bf16* __restrict__ krope, const __bf16* __restrict__ vT,
        __bf16* __restrict__ att) {
    const int flat = blockIdx.x;
    const int xcd = flat & 7;
    const int a0 = flat >> 3;
    const int bx = a0 & 7;
    const int g8 = ((a0 >> 3) << 3) | xcd;
    const int h = g8 & 15;
    const int b = g8 >> 4;

    const int tid = threadIdx.x;
    const int w  = tid >> 6;
    const int l  = tid & 63;
    const int lr = l & 15;
    const int lg = l >> 4;

    __shared__ __bf16 Ks[2][64][200];
    __shared__ __bf16 Vs[2][128][72];
    __shared__ __bf16 Ps[8][2][16][72];

    const int rg[2] = {bx * 128 + w * 16, (15 - bx) * 128 + w * 16};
    const int nkt = 2 * (15 - bx) + 2;

    bf16x8 sreg[5];
    auto stage_load = [&](int kv0) {
#pragma unroll
        for (int i = 0; i < 5; ++i) {
            const int gc = tid + 512 * i;
            if (gc < 1536) {
                const int row = gc / 24, cc = gc - row * 24;
                const size_t tt = (size_t)(b * SS + kv0 + row);
                const __bf16* src = (cc < 16)
                    ? knope + tt * 2048 + h * 128 + cc * 8
                    : krope + tt * 64 + (cc - 16) * 8;
                sreg[i] = *(const bf16x8*)src;
            } else {
                const int c = gc - 1536;
                const int row = c >> 3, cc = c & 7;
                sreg[i] = *(const bf16x8*)(vT + (((size_t)b * NHH + h) * 128 + row) * SS
                                              + kv0 + cc * 8);
            }
        }
    };
    auto stage_write = [&](int bi) {
#pragma unroll
        for (int i = 0; i < 5; ++i) {
            const int gc = tid + 512 * i;
            if (gc < 1536) {
                const int row = gc / 24, cc = gc - row * 24;
                *(bf16x8*)&Ks[bi][row][cc * 8] = sreg[i];
            } else {
                const int c = gc - 1536;
                *(bf16x8*)&Vs[bi][c >> 3][(c & 7) * 8] = sreg[i];
            }
        }
    };

    bf16x8 qf[2][6];
#pragma unroll
    for (int grp = 0; grp < 2; ++grp) {
        const __bf16* qb = q + (((size_t)(b * SS + rg[grp] + lr)) * NHH + h) * DQK + lg * 8;
#pragma unroll
        for (int c = 0; c < 6; ++c) qf[grp][c] = *(const bf16x8*)(qb + c * 32);
    }

    f32x4 O[2][8];
    float m_r[2][4], l_r[2][4];
#pragma unroll
    for (int grp = 0; grp < 2; ++grp) {
#pragma unroll
        for (int n = 0; n < 8; ++n) O[grp][n] = (f32x4){0.f, 0.f, 0.f, 0.f};
#pragma unroll
        for (int r = 0; r < 4; ++r) { m_r[grp][r] = -INFINITY; l_r[grp][r] = 0.f; }
    }

    stage_load(0);
    stage_write(0);
    __syncthreads();
    int cur = 0;

    for (int kt = 0; kt < nkt; ++kt) {
        const int kv0 = kt * 64;
        const bool hasNext = (kt + 1 < nkt);
        if (hasNext) stage_load(kv0 + 64);

        const bool act0 = kv0 <= rg[0] + 15;
        const bool act1 = kv0 <= rg[1] + 15;
        if (act1 || act0) {
            f32x4 sc[2][4];
#pragma unroll
            for (int s = 0; s < 4; ++s) {
                const int colb = kv0 + s * 16;
                if (colb <= rg[1] + 15 || colb <= rg[0] + 15) {
                    bf16x8 kf[6];
#pragma unroll
                    for (int c = 0; c < 6; ++c)
                        kf[c] = *(const bf16x8*)&Ks[cur][s * 16 + lr][c * 32 + lg * 8];
                    __builtin_amdgcn_s_setprio(1);
#pragma unroll
                    for (int grp = 0; grp < 2; ++grp) {
                        if (colb <= rg[grp] + 15) {
                            f32x4 acc = (f32x4){0.f, 0.f, 0.f, 0.f};
#pragma unroll
                            for (int c = 0; c < 6; ++c)
                                acc = __builtin_amdgcn_mfma_f32_16x16x32_bf16(qf[grp][c], kf[c], acc, 0, 0, 0);
                            sc[grp][s] = acc;
                        } else {
                            sc[grp][s] = (f32x4){-INFINITY, -INFINITY, -INFINITY, -INFINITY};
                        }
                    }
                    __builtin_amdgcn_s_setprio(0);
                } else {
                    sc[0][s] = (f32x4){-INFINITY, -INFINITY, -INFINITY, -INFINITY};
                    sc[1][s] = (f32x4){-INFINITY, -INFINITY, -INFINITY, -INFINITY};
                }
            }

#pragma unroll
            for (int grp = 0; grp < 2; ++grp) {
                const bool act = (grp == 0) ? act0 : act1;
                if (!act) continue;
                const int rgg = rg[grp];
#pragma unroll
                for (int s = 0; s < 4; ++s) {
                    const int col = kv0 + s * 16 + lr;
#pragma unroll
                    for (int r = 0; r < 4; ++r)
                        if (col > rgg + lg * 4 + r) sc[grp][s][r] = -INFINITY;
                }
                float mt[4];
#pragma unroll
                for (int r = 0; r < 4; ++r) {
                    float m = fmaxf(fmaxf(sc[grp][0][r], sc[grp][1][r]),
                                    fmaxf(sc[grp][2][r], sc[grp][3][r]));
                    m = fmaxf(m, __shfl_xor(m, 1));
                    m = fmaxf(m, __shfl_xor(m, 2));
                    m = fmaxf(m, __shfl_xor(m, 4));
                    m = fmaxf(m, __shfl_xor(m, 8));
                    mt[r] = m;
                }
                const bool ok = (mt[0] <= m_r[grp][0] + 8.f) && (mt[1] <= m_r[grp][1] + 8.f) &&
                                (mt[2] <= m_r[grp][2] + 8.f) && (mt[3] <= m_r[grp][3] + 8.f);
                if (!__all(ok)) {
#pragma unroll
                    for (int r = 0; r < 4; ++r) {
                        const float mn = fmaxf(m_r[grp][r], mt[r]);
                        const float al = __expf(m_r[grp][r] - mn);
                        m_r[grp][r] = mn;
                        l_r[grp][r] *= al;
#pragma unroll
                        for (int n = 0; n < 8; ++n) O[grp][n][r] *= al;
                    }
                }
#pragma unroll
                for (int s = 0; s < 4; ++s) {
#pragma unroll
                    for (int r = 0; r < 4; ++r) {
                        const float pv = __expf(sc[grp][s][r] - m_r[grp][r]);
                        sc[grp][s][r] = pv;
                        Ps[w][grp][lg * 4 + r][s * 16 + lr] = (__bf16)pv;
                    }
                }
#pragma unroll
                for (int r = 0; r < 4; ++r) {
                    float ls = (sc[grp][0][r] + sc[grp][1][r]) + (sc[grp][2][r] + sc[grp][3][r]);
                    ls += __shfl_xor(ls, 1);
                    ls += __shfl_xor(ls, 2);
                    ls += __shfl_xor(ls, 4);
                    ls += __shfl_xor(ls, 8);
                    l_r[grp][r] += ls;
                }
            }

            bf16x8 pf[2][2];
#pragma unroll
            for (int grp = 0; grp < 2; ++grp)
#pragma unroll
                for (int ks = 0; ks < 2; ++ks)
                    pf[grp][ks] = *(const bf16x8*)&Ps[w][grp][lr][ks * 32 + lg * 8];
#pragma unroll
            for (int n = 0; n < 8; ++n) {
                bf16x8 v0 = *(const bf16x8*)&Vs[cur][n * 16 + lr][lg * 8];
                bf16x8 v1 = *(const bf16x8*)&Vs[cur][n * 16 + lr][32 + lg * 8];
                __builtin_amdgcn_s_setprio(1);
                if (act0) {
                    O[0][n] = __builtin_amdgcn_mfma_f32_16x16x32_bf16(pf[0][0], v0, O[0][n], 0, 0, 0);
                    O[0][n] = __builtin_amdgcn_mfma_f32_16x16x32_bf16(pf[0][1], v1, O[0][n], 0, 0, 0);
                }
                if (act1) {
                    O[1][n] = __builtin_amdgcn_mfma_f32_16x16x32_bf16(pf[1][0], v0, O[1][n], 0, 0, 0);
                    O[1][n] = __builtin_amdgcn_mfma_f32_16x16x32_bf16(pf[1][1], v1, O[1][n], 0, 0, 0);
                }
                __builtin_amdgcn_s_setprio(0);
            }
        }

        if (hasNext) stage_write(cur ^ 1);
        __syncthreads();
        cur ^= 1;
    }

#pragma unroll
    for (int grp = 0; grp < 2; ++grp) {
        float inv[4];
#pragma unroll
        for (int r = 0; r < 4; ++r) inv[r] = 1.0f / l_r[grp][r];
#pragma unroll
        for (int n = 0; n < 8; ++n) {
#pragma unroll
            for (int r = 0; r < 4; ++r) {
                const size_t tt = (size_t)(b * SS + rg[grp] + lg * 4 + r);
                att[(tt * NHH + h) * 128 + n * 16 + lr] = (__bf16)(O[grp][n][r] * inv[r]);
            }
        }
    }
}

// ---------------------------------------------------------------------------
extern "C" void kernel_launch(void* const* d_in, const int* in_sizes, int n_in,
                              void* d_out, int out_size, void* d_ws, size_t ws_size,
                              hipStream_t stream) {
    (void)in_sizes; (void)n_in; (void)out_size; (void)ws_size;
    const float* x        = (const float*)d_in[0];
    const float* wq_down  = (const float*)d_in[1];
    const float* wq_up    = (const float*)d_in[2];
    const float* wq_rope  = (const float*)d_in[3];
    const float* q_norm_w = (const float*)d_in[4];
    const float* wkv_down = (const float*)d_in[5];
    const float* kv_norm_w= (const float*)d_in[6];
    const float* wkv_up   = (const float*)d_in[7];
    const float* wk_rope  = (const float*)d_in[8];
    const float* wo       = (const float*)d_in[9];
    float* out = (float*)d_out;

    char* ws = (char*)d_ws;
    float*  q_c   = (float*)(ws + 0);            // 24MB fp32 [4096][1536]
    __bf16* att   = (__bf16*)(ws + 0);           // 16MB bf16, aliases dead q_c
    float*  kv_c  = (float*)(ws + 25165824);     // 8MB fp32 [4096][512]
    __bf16* xb    = (__bf16*)(ws + 33554432);    // 16MB bf16 [4096][2048]
    __bf16* vT    = (__bf16*)(ws + 33554432);    // 16MB bf16, aliases dead xb
    __bf16* qc_b  = (__bf16*)(ws + 50331648);    // 12MB bf16 [4096][1536]
    __bf16* kvc_b = (__bf16*)(ws + 62914560);    // 4MB bf16 [4096][512]
    __bf16* krope = (__bf16*)(ws + 67108864);    // 0.5MB bf16 [4096][64]
    __bf16* qbuf  = (__bf16*)(ws + 67633152);    // 24MB bf16 [4096][3072]
    __bf16* wqd_b = (__bf16*)(ws + 92798976);    // 6MB
    __bf16* wqu_b = (__bf16*)(ws + 99090432);    // 6MB
    __bf16* wqr_b = (__bf16*)(ws + 105381888);   // 3MB
    __bf16* wkvd_b= (__bf16*)(ws + 108527616);   // 2MB
    __bf16* wkvu_b= (__bf16*)(ws + 110624768);   // 4MB
    __bf16* wkr_b = (__bf16*)(ws + 114819072);   // 0.25MB
    __bf16* wo_b  = (__bf16*)(ws + 115081216);   // 8MB (end 123469824)
    __bf16* knope = (__bf16*)d_out;              // 16MB bf16 in d_out (dead until final GEMM)

    const dim3 blk(256);

    cast_all<<<dim3(SEG7 / 2048), blk, 0, stream>>>(
        x, wq_down, wkv_down, wk_rope, wq_up, wq_rope, wkv_up, wo,
        xb, wqd_b, wkvd_b, wkr_b, wqu_b, wqr_b, wkvu_b, wo_b);

    // X-GEMM: 256 full tiles + 32 cheap strip tiles
    gemm10<0><<<dim3(288), dim3(512), 0, stream>>>(xb, wqd_b, wkvd_b, wkr_b,
                                                   q_c, kv_c, krope, nullptr, TT, 2112, 2048);

    rmsnorm_k<<<dim3(TT), blk, 0, stream>>>(q_c, qc_b, q_norm_w, 1536);
    rmsnorm_k<<<dim3(TT), blk, 0, stream>>>(kv_c, kvc_b, kv_norm_w, 512);

    // fused Q-GEMM (384 tiles) + KV-GEMM (512 tiles) in one 896-block launch
    gemm10<1><<<dim3(896), dim3(512), 0, stream>>>(qc_b, wqu_b, wqr_b, wkvu_b,
                                                   (float*)kvc_b, (float*)vT,
                                                   qbuf, knope, TT, 3072, 1536);

    attn_mfma7<<<dim3(256), dim3(512), 0, stream>>>(qbuf, knope, krope, vT, att);

    gemm10<3><<<dim3(8, 32), dim3(512), 0, stream>>>(att, wo_b, nullptr, nullptr,
                                                     out, nullptr, nullptr, nullptr, TT, 2048, 2048);
}

// Round 14
// 299.252 us; speedup vs baseline: 1.3825x; 1.0764x over previous
//
#include <hip/hip_runtime.h>
#include <hip/hip_bf16.h>
#include <math.h>

#define NHH 16
#define SS  2048
#define TT  4096            // B*S tokens
#define DQK 192
#define QSCALE 0.07216878364870322f   // 1/sqrt(192)
#define ROPE_C 0.28782313662425574f   // 2*ln(10000)/64

typedef __bf16 bf16x8 __attribute__((ext_vector_type(8)));
typedef float f32x4 __attribute__((ext_vector_type(4)));
typedef unsigned long long u64;

#define GLOAD16(gp, lp) __builtin_amdgcn_global_load_lds( \
    (const __attribute__((address_space(1))) void*)(gp),  \
    (__attribute__((address_space(3))) void*)(lp), 16, 0, 0)

// ---------------------------------------------------------------------------
// Fused fp32 -> bf16 cast of x + all 7 weight tensors.
// ---------------------------------------------------------------------------
#define SEG0 8388608     // x
#define SEG1 11534336    // + wq_down (3145728)
#define SEG2 12582912    // + wkv_down (1048576)
#define SEG3 12713984    // + wk_rope (131072)
#define SEG4 15859712    // + wq_up (3145728)
#define SEG5 17432576    // + wq_rope (1572864)
#define SEG6 19529728    // + wkv_up (2097152)
#define SEG7 23724032    // + wo (4194304)

__global__ __launch_bounds__(256) void cast_all(
        const float* __restrict__ x, const float* __restrict__ wqd,
        const float* __restrict__ wkvd, const float* __restrict__ wkr,
        const float* __restrict__ wqu, const float* __restrict__ wqr,
        const float* __restrict__ wkvu, const float* __restrict__ wo,
        __bf16* __restrict__ xb, __bf16* __restrict__ wqd_b,
        __bf16* __restrict__ wkvd_b, __bf16* __restrict__ wkr_b,
        __bf16* __restrict__ wqu_b, __bf16* __restrict__ wqr_b,
        __bf16* __restrict__ wkvu_b, __bf16* __restrict__ wo_b) {
    const int i = (blockIdx.x * 256 + threadIdx.x) * 8;
    const float* src;
    __bf16* dst;
    int off;
    if (i < SEG0)      { src = x;    dst = xb;     off = i; }
    else if (i < SEG1) { src = wqd;  dst = wqd_b;  off = i - SEG0; }
    else if (i < SEG2) { src = wkvd; dst = wkvd_b; off = i - SEG1; }
    else if (i < SEG3) { src = wkr;  dst = wkr_b;  off = i - SEG2; }
    else if (i < SEG4) { src = wqu;  dst = wqu_b;  off = i - SEG3; }
    else if (i < SEG5) { src = wqr;  dst = wqr_b;  off = i - SEG4; }
    else if (i < SEG6) { src = wkvu; dst = wkvu_b; off = i - SEG5; }
    else               { src = wo;   dst = wo_b;   off = i - SEG6; }
    const float4 a = *(const float4*)(src + off);
    const float4 b = *(const float4*)(src + off + 4);
    __bf16 o[8] = {(__bf16)a.x, (__bf16)a.y, (__bf16)a.z, (__bf16)a.w,
                   (__bf16)b.x, (__bf16)b.y, (__bf16)b.z, (__bf16)b.w};
    *(bf16x8*)(dst + off) = *(const bf16x8*)o;
}

// ---------------------------------------------------------------------------
// RMSNorm: fp32 in -> bf16 out
// ---------------------------------------------------------------------------
__global__ __launch_bounds__(256) void rmsnorm_k(const float* __restrict__ in,
                                                 __bf16* __restrict__ out,
                                                 const float* __restrict__ w, int N) {
    const int row = blockIdx.x;
    const float* xr = in + (size_t)row * N;
    float ss = 0.f;
    for (int i = threadIdx.x; i < N; i += 256) {
        float v = xr[i];
        ss += v * v;
    }
    __shared__ float red[256];
    red[threadIdx.x] = ss;
    __syncthreads();
    for (int s = 128; s > 0; s >>= 1) {
        if (threadIdx.x < s) red[threadIdx.x] += red[threadIdx.x + s];
        __syncthreads();
    }
    const float scale = rsqrtf(red[0] / (float)N + 1e-6f);
    __bf16* orow = out + (size_t)row * N;
    for (int i = threadIdx.x; i < N; i += 256) orow[i] = (__bf16)(xr[i] * scale * w[i]);
}

// ---------------------------------------------------------------------------
// bf16 MFMA NT-GEMM v3 (unchanged from passing R13): BK=32, 3-buffer LDS at
// 72KB -> 2 blocks/CU; one barrier + one counted vmcnt per K-tile.
// ---------------------------------------------------------------------------
template<int MODE>
__global__ __launch_bounds__(512, 2) void gemm10(
        const __bf16* __restrict__ A,
        const __bf16* __restrict__ W0, const __bf16* __restrict__ W1,
        const __bf16* __restrict__ W2,
        float* __restrict__ F0, float* __restrict__ F1,
        __bf16* __restrict__ B0, __bf16* __restrict__ B1,
        int M, int N, int Kin) {
    __shared__ __bf16 lds[3 * 12288];   // 3 x (A 128x32 + B 256x32) = 72KB
    const int tid = threadIdx.x;
    const int w = tid >> 6, l = tid & 63;
    const int lr = l & 15, lg = l >> 4;
    const int wm = w >> 2, wn = w & 3;

    int m0, n0, nlim = 256, K = Kin;
    bool isKV = false;
    const __bf16* Ause = A;
    if (MODE == 0) {
        const int fb = blockIdx.x;
        if (fb < 256) { m0 = (fb >> 3) * 128; n0 = (fb & 7) * 256; }
        else          { m0 = (fb - 256) * 128; n0 = 2048; }
        nlim = 2112 - n0;
    } else if (MODE == 1) {
        int fb = blockIdx.x;
        isKV = (fb >= 384);
        if (isKV) { fb -= 384; K = 512; Ause = (const __bf16*)F0; }
        m0 = (fb & 31) * 128;
        n0 = (fb >> 5) * 256;
    } else {
        m0 = blockIdx.y * 128; n0 = blockIdx.x * 256;
    }
    const bool fullB = (nlim >= 256);
    const bool wAct  = (wn * 64 < nlim);

    const int srow = tid >> 2;              // 0..127
    const int scol = (tid & 3) << 3;        // 0,8,16,24
    const int csw  = scol ^ (((srow >> 1) & 3) << 3);

    const __bf16* aptr = Ause + (size_t)(m0 + srow) * K + csw;

    const __bf16* bptr[2];
#pragma unroll
    for (int i = 0; i < 2; ++i) {
        const int row = i * 128 + srow;
        const int n = n0 + row;
        const __bf16* wp;
        if (MODE == 0) {
            if (n < 1536)      wp = W0 + (size_t)n * K;
            else if (n < 2048) wp = W1 + (size_t)(n - 1536) * K;
            else if (n < 2112) wp = W2 + (size_t)(n - 2048) * K;
            else               wp = W0;
        } else if (MODE == 1) {
            if (isKV)          wp = W2 + (size_t)n * K;
            else               wp = (n < 2048) ? W0 + (size_t)n * K
                                               : W1 + (size_t)(n - 2048) * K;
        } else {
            wp = W0 + (size_t)n * K;
        }
        bptr[i] = wp + csw;
    }

    auto stA = [&](int t2) {
        GLOAD16(aptr + (size_t)t2 * 32, &lds[(t2 % 3) * 12288 + tid * 8]);
    };
    auto stB = [&](int t2, int i) {
        GLOAD16(bptr[i] + (size_t)t2 * 32,
                &lds[(t2 % 3) * 12288 + 4096 + i * 4096 + tid * 8]);
    };

    const int rswz = ((lr >> 1) & 3) << 3;

    f32x4 acc[4][4];
#pragma unroll
    for (int i = 0; i < 4; ++i)
#pragma unroll
        for (int j = 0; j < 4; ++j) acc[i][j] = (f32x4){0.f, 0.f, 0.f, 0.f};

    const int NT = K >> 5;
    stA(0); stB(0, 0); if (fullB) stB(0, 1);
    stA(1); stB(1, 0); if (fullB) stB(1, 1);

    for (int t = 0; t < NT; ++t) {
        if (t + 1 < NT) {
            if (fullB) asm volatile("s_waitcnt vmcnt(3)" ::: "memory");
            else       asm volatile("s_waitcnt vmcnt(2)" ::: "memory");
        } else {
            asm volatile("s_waitcnt vmcnt(0)" ::: "memory");
        }
        __builtin_amdgcn_s_barrier();

        const __bf16* As_ = &lds[(t % 3) * 12288];
        const __bf16* Bs_ = As_ + 4096;

        if (t + 2 < NT) {
            stA(t + 2); stB(t + 2, 0); if (fullB) stB(t + 2, 1);
        }

        if (wAct) {
            bf16x8 fa[4], fb[4];
#pragma unroll
            for (int i = 0; i < 4; ++i)
                fa[i] = *(const bf16x8*)&As_[(wm * 64 + i * 16 + lr) * 32 +
                                             ((lg * 8) ^ rswz)];
#pragma unroll
            for (int j = 0; j < 4; ++j)
                fb[j] = *(const bf16x8*)&Bs_[(wn * 64 + j * 16 + lr) * 32 +
                                             ((lg * 8) ^ rswz)];
            __builtin_amdgcn_s_setprio(1);
#pragma unroll
            for (int i = 0; i < 4; ++i)
#pragma unroll
                for (int j = 0; j < 4; ++j)
                    acc[i][j] = __builtin_amdgcn_mfma_f32_16x16x32_bf16(fa[i], fb[j], acc[i][j], 0, 0, 0);
            __builtin_amdgcn_s_setprio(0);
        }
    }

    if (!wAct) return;

#pragma unroll
    for (int i = 0; i < 4; ++i) {
#pragma unroll
        for (int j = 0; j < 4; ++j) {
#pragma unroll
            for (int r = 0; r < 4; ++r) {
                const int m = m0 + wm * 64 + i * 16 + lg * 4 + r;
                const int n = n0 + wn * 64 + j * 16 + lr;
                const float v = acc[i][j][r];
                float vp = 0.f;
                if (MODE == 0 || MODE == 1) vp = __shfl_xor(v, 1);  // rope partner
                if (MODE == 0) {
                    if (n < 1536) {
                        F0[(size_t)m * 1536 + n] = v;
                    } else if (n < 2048) {
                        F1[(size_t)m * 512 + (n - 1536)] = v;
                    } else if (n < 2112) {
                        const int jj = n - 2048;
                        const int fi = jj >> 1;
                        const int spos = m & (SS - 1);
                        const float freq = __expf(-ROPE_C * (float)fi);
                        const float ang = (float)spos * freq;
                        const float sn = __sinf(ang), cs = __cosf(ang);
                        const float o = (jj & 1) ? (vp * sn + v * cs) : (v * cs - vp * sn);
                        B0[(size_t)m * 64 + jj] = (__bf16)o;
                    }
                } else if (MODE == 1) {
                    if (!isKV) {
                        if (n < 2048) {
                            B0[(size_t)m * 3072 + (n >> 7) * 192 + (n & 127)] = (__bf16)(v * QSCALE);
                        } else {
                            const int jj = n - 2048;
                            const int h = jj >> 6, dd = jj & 63;
                            const int fi = dd >> 1;
                            const int spos = m & (SS - 1);
                            const float freq = __expf(-ROPE_C * (float)fi);
                            const float ang = (float)spos * freq;
                            const float sn = __sinf(ang), cs = __cosf(ang);
                            const float o = (dd & 1) ? (vp * sn + v * cs) : (v * cs - vp * sn);
                            B0[(size_t)m * 3072 + h * 192 + 128 + dd] = (__bf16)(o * QSCALE);
                        }
                    } else {
                        __bf16* vTo = (__bf16*)F1;
                        const int h = n >> 8, off = n & 255;
                        if (off < 128)
                            B1[(size_t)m * 2048 + h * 128 + off] = (__bf16)v;
                        else
                            vTo[(((size_t)(m >> 11) * NHH + h) * 128 + (off - 128)) * SS + (m & (SS - 1))] = (__bf16)v;
                    }
                } else {
                    F0[(size_t)m * N + n] = v;
                }
            }
        }
    }
}

// ---------------------------------------------------------------------------
// MFMA flash attention v9: swapped-operand QK^T.
// sc = mfma(K, Q) -> D[kv][q]: lane lr = q-row, regs (s, lg*4+r) = kv.
// Softmax is per-lane (one q-row per lane): in-lane 16-val tree + shfl_xor
// 16/32. P store: 4 consecutive kv per lane -> ds_write_b64 into the SAME
// [q][kv] pitch-72 matrix the old code built; P read + PV + staging +
// epilogue identical to R13's passing code (alpha/inv broadcast via shfl).
// ---------------------------------------------------------------------------
__global__ __launch_bounds__(512, 1) void attn_mfma9(
        const __bf16* __restrict__ q, const __bf16* __restrict__ knope,
        const __bf16* __restrict__ krope, const __bf16* __restrict__ vT,
        __bf16* __restrict__ att) {
    const int flat = blockIdx.x;
    const int xcd = flat & 7;
    const int a0 = flat >> 3;
    const int bx = a0 & 7;
    const int g8 = ((a0 >> 3) << 3) | xcd;
    const int h = g8 & 15;
    const int b = g8 >> 4;

    const int tid = threadIdx.x;
    const int w  = tid >> 6;
    const int l  = tid & 63;
    const int lr = l & 15;
    const int lg = l >> 4;

    __shared__ __bf16 Ks[2][64][200];
    __shared__ __bf16 Vs[2][128][72];
    __shared__ __bf16 Ps[8][2][16][72];

    const int rg[2] = {bx * 128 + w * 16, (15 - bx) * 128 + w * 16};
    const int nkt = 2 * (15 - bx) + 2;

    bf16x8 sreg[5];
    auto stage_load = [&](int kv0) {
#pragma unroll
        for (int i = 0; i < 5; ++i) {
            const int gc = tid + 512 * i;
            if (gc < 1536) {
                const int row = gc / 24, cc = gc - row * 24;
                const size_t tt = (size_t)(b * SS + kv0 + row);
                const __bf16* src = (cc < 16)
                    ? knope + tt * 2048 + h * 128 + cc * 8
                    : krope + tt * 64 + (cc - 16) * 8;
                sreg[i] = *(const bf16x8*)src;
            } else {
                const int c = gc - 1536;
                const int row = c >> 3, cc = c & 7;
                sreg[i] = *(const bf16x8*)(vT + (((size_t)b * NHH + h) * 128 + row) * SS
                                              + kv0 + cc * 8);
            }
        }
    };
    auto stage_write = [&](int bi) {
#pragma unroll
        for (int i = 0; i < 5; ++i) {
            const int gc = tid + 512 * i;
            if (gc < 1536) {
                const int row = gc / 24, cc = gc - row * 24;
                *(bf16x8*)&Ks[bi][row][cc * 8] = sreg[i];
            } else {
                const int c = gc - 1536;
                *(bf16x8*)&Vs[bi][c >> 3][(c & 7) * 8] = sreg[i];
            }
        }
    };

    bf16x8 qf[2][6];
#pragma unroll
    for (int grp = 0; grp < 2; ++grp) {
        const __bf16* qb = q + (((size_t)(b * SS + rg[grp] + lr)) * NHH + h) * DQK + lg * 8;
#pragma unroll
        for (int c = 0; c < 6; ++c) qf[grp][c] = *(const bf16x8*)(qb + c * 32);
    }

    f32x4 O[2][8];
    float m_s[2], l_s[2];
#pragma unroll
    for (int grp = 0; grp < 2; ++grp) {
#pragma unroll
        for (int n = 0; n < 8; ++n) O[grp][n] = (f32x4){0.f, 0.f, 0.f, 0.f};
        m_s[grp] = -INFINITY; l_s[grp] = 0.f;
    }

    stage_load(0);
    stage_write(0);
    __syncthreads();
    int cur = 0;

    for (int kt = 0; kt < nkt; ++kt) {
        const int kv0 = kt * 64;
        const bool hasNext = (kt + 1 < nkt);
        if (hasNext) stage_load(kv0 + 64);

        const bool act0 = kv0 <= rg[0] + 15;
        const bool act1 = kv0 <= rg[1] + 15;
        if (act1 || act0) {
            // ---- QK^T (swapped): D[kv][q], lane lr = q-row ----
            f32x4 sc[2][4];
#pragma unroll
            for (int s = 0; s < 4; ++s) {
                const int colb = kv0 + s * 16;
                if (colb <= rg[1] + 15 || colb <= rg[0] + 15) {
                    bf16x8 kf[6];
#pragma unroll
                    for (int c = 0; c < 6; ++c)
                        kf[c] = *(const bf16x8*)&Ks[cur][s * 16 + lr][c * 32 + lg * 8];
                    __builtin_amdgcn_s_setprio(1);
#pragma unroll
                    for (int grp = 0; grp < 2; ++grp) {
                        if (colb <= rg[grp] + 15) {
                            f32x4 acc = (f32x4){0.f, 0.f, 0.f, 0.f};
#pragma unroll
                            for (int c = 0; c < 6; ++c)
                                acc = __builtin_amdgcn_mfma_f32_16x16x32_bf16(kf[c], qf[grp][c], acc, 0, 0, 0);
                            sc[grp][s] = acc;
                        } else {
                            sc[grp][s] = (f32x4){-INFINITY, -INFINITY, -INFINITY, -INFINITY};
                        }
                    }
                    __builtin_amdgcn_s_setprio(0);
                } else {
                    sc[0][s] = (f32x4){-INFINITY, -INFINITY, -INFINITY, -INFINITY};
                    sc[1][s] = (f32x4){-INFINITY, -INFINITY, -INFINITY, -INFINITY};
                }
            }

            // ---- per-lane softmax (defer-max) + vector P store ----
#pragma unroll
            for (int grp = 0; grp < 2; ++grp) {
                const bool act = (grp == 0) ? act0 : act1;
                if (!act) continue;
                const int qrow = rg[grp] + lr;      // this lane's q-row
                // causal mask: kv = kv0 + s*16 + lg*4 + r
#pragma unroll
                for (int s = 0; s < 4; ++s) {
#pragma unroll
                    for (int r = 0; r < 4; ++r)
                        if (kv0 + s * 16 + lg * 4 + r > qrow) sc[grp][s][r] = -INFINITY;
                }
                // row max: in-lane 16 -> cross-lg
                float mt = sc[grp][0][0];
#pragma unroll
                for (int s = 0; s < 4; ++s)
#pragma unroll
                    for (int r = 0; r < 4; ++r) mt = fmaxf(mt, sc[grp][s][r]);
                mt = fmaxf(mt, __shfl_xor(mt, 16));
                mt = fmaxf(mt, __shfl_xor(mt, 32));
                const bool ok = (mt <= m_s[grp] + 8.f);
                if (!__all(ok)) {
                    const float mn = fmaxf(m_s[grp], mt);
                    const float al = __expf(m_s[grp] - mn);
                    m_s[grp] = mn;
                    l_s[grp] *= al;
                    float al4[4];
#pragma unroll
                    for (int r = 0; r < 4; ++r) al4[r] = __shfl(al, lg * 4 + r);
#pragma unroll
                    for (int n = 0; n < 8; ++n)
#pragma unroll
                        for (int r = 0; r < 4; ++r) O[grp][n][r] *= al4[r];
                }
                // P = exp(sc - m), pack 4 consecutive kv -> ds_write_b64
                float ls = 0.f;
#pragma unroll
                for (int s = 0; s < 4; ++s) {
                    float pv[4];
#pragma unroll
                    for (int r = 0; r < 4; ++r) pv[r] = __expf(sc[grp][s][r] - m_s[grp]);
                    ls += (pv[0] + pv[1]) + (pv[2] + pv[3]);
                    union { __bf16 hh[4]; u64 u; } pk;
                    pk.hh[0] = (__bf16)pv[0]; pk.hh[1] = (__bf16)pv[1];
                    pk.hh[2] = (__bf16)pv[2]; pk.hh[3] = (__bf16)pv[3];
                    *(u64*)&Ps[w][grp][lr][s * 16 + lg * 4] = pk.u;
                }
                ls += __shfl_xor(ls, 16);
                ls += __shfl_xor(ls, 32);
                l_s[grp] += ls;
            }

            // ---- P read + PV (identical to R13) ----
            bf16x8 pf[2][2];
#pragma unroll
            for (int grp = 0; grp < 2; ++grp)
#pragma unroll
                for (int ks = 0; ks < 2; ++ks)
                    pf[grp][ks] = *(const bf16x8*)&Ps[w][grp][lr][ks * 32 + lg * 8];
#pragma unroll
            for (int n = 0; n < 8; ++n) {
                bf16x8 v0 = *(const bf16x8*)&Vs[cur][n * 16 + lr][lg * 8];
                bf16x8 v1 = *(const bf16x8*)&Vs[cur][n * 16 + lr][32 + lg * 8];
                __builtin_amdgcn_s_setprio(1);
                if (act0) {
                    O[0][n] = __builtin_amdgcn_mfma_f32_16x16x32_bf16(pf[0][0], v0, O[0][n], 0, 0, 0);
                    O[0][n] = __builtin_amdgcn_mfma_f32_16x16x32_bf16(pf[0][1], v1, O[0][n], 0, 0, 0);
                }
                if (act1) {
                    O[1][n] = __builtin_amdgcn_mfma_f32_16x16x32_bf16(pf[1][0], v0, O[1][n], 0, 0, 0);
                    O[1][n] = __builtin_amdgcn_mfma_f32_16x16x32_bf16(pf[1][1], v1, O[1][n], 0, 0, 0);
                }
                __builtin_amdgcn_s_setprio(0);
            }
        }

        if (hasNext) stage_write(cur ^ 1);
        __syncthreads();
        cur ^= 1;
    }

    // ---- epilogue (inv broadcast via shfl) ----
#pragma unroll
    for (int grp = 0; grp < 2; ++grp) {
        const float invl = 1.0f / l_s[grp];
        float inv[4];
#pragma unroll
        for (int r = 0; r < 4; ++r) inv[r] = __shfl(invl, lg * 4 + r);
#pragma unroll
        for (int n = 0; n < 8; ++n) {
#pragma unroll
            for (int r = 0; r < 4; ++r) {
                const size_t tt = (size_t)(b * SS + rg[grp] + lg * 4 + r);
                att[(tt * NHH + h) * 128 + n * 16 + lr] = (__bf16)(O[grp][n][r] * inv[r]);
            }
        }
    }
}

// ---------------------------------------------------------------------------
extern "C" void kernel_launch(void* const* d_in, const int* in_sizes, int n_in,
                              void* d_out, int out_size, void* d_ws, size_t ws_size,
                              hipStream_t stream) {
    (void)in_sizes; (void)n_in; (void)out_size; (void)ws_size;
    const float* x        = (const float*)d_in[0];
    const float* wq_down  = (const float*)d_in[1];
    const float* wq_up    = (const float*)d_in[2];
    const float* wq_rope  = (const float*)d_in[3];
    const float* q_norm_w = (const float*)d_in[4];
    const float* wkv_down = (const float*)d_in[5];
    const float* kv_norm_w= (const float*)d_in[6];
    const float* wkv_up   = (const float*)d_in[7];
    const float* wk_rope  = (const float*)d_in[8];
    const float* wo       = (const float*)d_in[9];
    float* out = (float*)d_out;

    char* ws = (char*)d_ws;
    float*  q_c   = (float*)(ws + 0);            // 24MB fp32 [4096][1536]
    __bf16* att   = (__bf16*)(ws + 0);           // 16MB bf16, aliases dead q_c
    float*  kv_c  = (float*)(ws + 25165824);     // 8MB fp32 [4096][512]
    __bf16* xb    = (__bf16*)(ws + 33554432);    // 16MB bf16 [4096][2048]
    __bf16* vT    = (__bf16*)(ws + 33554432);    // 16MB bf16, aliases dead xb
    __bf16* qc_b  = (__bf16*)(ws + 50331648);    // 12MB bf16 [4096][1536]
    __bf16* kvc_b = (__bf16*)(ws + 62914560);    // 4MB bf16 [4096][512]
    __bf16* krope = (__bf16*)(ws + 67108864);    // 0.5MB bf16 [4096][64]
    __bf16* qbuf  = (__bf16*)(ws + 67633152);    // 24MB bf16 [4096][3072]
    __bf16* wqd_b = (__bf16*)(ws + 92798976);    // 6MB
    __bf16* wqu_b = (__bf16*)(ws + 99090432);    // 6MB
    __bf16* wqr_b = (__bf16*)(ws + 105381888);   // 3MB
    __bf16* wkvd_b= (__bf16*)(ws + 108527616);   // 2MB
    __bf16* wkvu_b= (__bf16*)(ws + 110624768);   // 4MB
    __bf16* wkr_b = (__bf16*)(ws + 114819072);   // 0.25MB
    __bf16* wo_b  = (__bf16*)(ws + 115081216);   // 8MB (end 123469824)
    __bf16* knope = (__bf16*)d_out;              // 16MB bf16 in d_out (dead until final GEMM)

    const dim3 blk(256);

    cast_all<<<dim3(SEG7 / 2048), blk, 0, stream>>>(
        x, wq_down, wkv_down, wk_rope, wq_up, wq_rope, wkv_up, wo,
        xb, wqd_b, wkvd_b, wkr_b, wqu_b, wqr_b, wkvu_b, wo_b);

    // X-GEMM: 256 full tiles + 32 cheap strip tiles
    gemm10<0><<<dim3(288), dim3(512), 0, stream>>>(xb, wqd_b, wkvd_b, wkr_b,
                                                   q_c, kv_c, krope, nullptr, TT, 2112, 2048);

    rmsnorm_k<<<dim3(TT), blk, 0, stream>>>(q_c, qc_b, q_norm_w, 1536);
    rmsnorm_k<<<dim3(TT), blk, 0, stream>>>(kv_c, kvc_b, kv_norm_w, 512);

    // fused Q-GEMM (384 tiles) + KV-GEMM (512 tiles) in one 896-block launch
    gemm10<1><<<dim3(896), dim3(512), 0, stream>>>(qc_b, wqu_b, wqr_b, wkvu_b,
                                                   (float*)kvc_b, (float*)vT,
                                                   qbuf, knope, TT, 3072, 1536);

    attn_mfma9<<<dim3(256), dim3(512), 0, stream>>>(qbuf, knope, krope, vT, att);

    gemm10<3><<<dim3(8, 32), dim3(512), 0, stream>>>(att, wo_b, nullptr, nullptr,
                                                     out, nullptr, nullptr, nullptr, TT, 2048, 2048);
}